// Round 4
// baseline (722.491 us; speedup 1.0000x reference)
//
#include <hip/hip_runtime.h>
#include <hip/hip_bf16.h>
#include <math.h>

#define NN 50000
#define NE 800000
#define C  128
#define CT 16        // channel tile: 50000*16*4B = 3.2 MB fits a 4 MB XCD L2
typedef unsigned int u32;

using f32x4  = __attribute__((ext_vector_type(4))) float;
using short8 = __attribute__((ext_vector_type(8))) short;

__device__ __forceinline__ unsigned short f2bf(float f) {
    unsigned int u = __float_as_uint(f);
    unsigned int r = u + 0x7FFFu + ((u >> 16) & 1u);
    return (unsigned short)(r >> 16);
}
__device__ __forceinline__ float bf2f(unsigned short h) {
    return __uint_as_float(((unsigned int)h) << 16);
}

// global(per-lane src) -> LDS(uniform base, lane*16B), 16B per lane
__device__ __forceinline__ void gload_lds16(const unsigned short* g, unsigned short* l) {
    __builtin_amdgcn_global_load_lds(
        (const __attribute__((address_space(1))) u32*)g,
        (__attribute__((address_space(3))) u32*)l,
        16, 0, 0);
}

// ---------------- CSR build ----------------

__global__ void k_zero(int* __restrict__ p, int n) {
    int i = blockIdx.x * blockDim.x + threadIdx.x;
    if (i < n) p[i] = 0;
}

__global__ void k_hist(const int* __restrict__ dst, int* __restrict__ deg, int nE) {
    int e = blockIdx.x * blockDim.x + threadIdx.x;
    if (e < nE) atomicAdd(&deg[dst[e]], 1);
}

__global__ __launch_bounds__(1024) void k_scan_blk(const int* __restrict__ deg, int* __restrict__ rowptr,
                                                   int* __restrict__ bsum, int n) {
    __shared__ int wsum[16];
    int tid = threadIdx.x, lane = tid & 63, wid = tid >> 6;
    int i = blockIdx.x * 1024 + tid;
    int v = (i < n) ? deg[i] : 0;
    int incl = v;
    #pragma unroll
    for (int d = 1; d < 64; d <<= 1) {
        int t = __shfl_up(incl, d, 64);
        if (lane >= d) incl += t;
    }
    if (lane == 63) wsum[wid] = incl;
    __syncthreads();
    int wo = 0;
    #pragma unroll
    for (int w = 0; w < 16; ++w) wo += (w < wid) ? wsum[w] : 0;
    if (i < n) rowptr[i + 1] = wo + incl;
    if (tid == 1023) bsum[blockIdx.x] = wo + incl;
}

__global__ void k_scan_sums(int* __restrict__ bsum, int nb) {
    int lane = threadIdx.x;
    int v = (lane < nb) ? bsum[lane] : 0;
    int incl = v;
    #pragma unroll
    for (int d = 1; d < 64; d <<= 1) {
        int t = __shfl_up(incl, d, 64);
        if (lane >= d) incl += t;
    }
    if (lane < nb) bsum[lane] = incl - v;  // exclusive
}

__global__ __launch_bounds__(1024) void k_scan_add(int* __restrict__ rowptr, const int* __restrict__ bsum, int n) {
    int i = blockIdx.x * 1024 + threadIdx.x;
    if (i == 0) rowptr[0] = 0;
    if (i < n) rowptr[i + 1] += bsum[blockIdx.x];
}

__global__ void k_fill(const int* __restrict__ src, const int* __restrict__ dst,
                       const int* __restrict__ rowptr, int* __restrict__ cursor,
                       int* __restrict__ esrc, int nE) {
    int e = blockIdx.x * blockDim.x + threadIdx.x;
    if (e < nE) {
        int d   = dst[e];
        int pos = rowptr[d] + atomicAdd(&cursor[d], 1);
        esrc[pos] = src[e];
    }
}

// ---------------- segment max: wave-per-node, channel-tiled ----------------
// lane = slot*16 + cl : 4 edge slots x 16 channels; 2 gathers in flight/lane.
// Index clamp instead of branch (max is idempotent). grid = (NN/4, C/CT).
__global__ __launch_bounds__(256) void k_segmax_w(const float* __restrict__ h, const int* __restrict__ rowptr,
                                                  const int* __restrict__ esrc, float* __restrict__ agg, int n) {
    int node = blockIdx.x * 4 + (threadIdx.x >> 6);
    int lane = threadIdx.x & 63;
    int slot = lane >> 4, cl = lane & 15;
    int c    = blockIdx.y * CT + cl;
    if (node >= n) return;
    int beg = rowptr[node], end = rowptr[node + 1];
    float m = -INFINITY;
    for (int i = beg; i < end; i += 8) {
        int e0 = i + slot;     if (e0 > end - 1) e0 = end - 1;
        int e1 = i + 4 + slot; if (e1 > end - 1) e1 = end - 1;
        int s0 = esrc[e0], s1 = esrc[e1];
        m = fmaxf(m, h[(size_t)s0 * C + c]);
        m = fmaxf(m, h[(size_t)s1 * C + c]);
    }
    m = fmaxf(m, __shfl_xor(m, 16, 64));
    m = fmaxf(m, __shfl_xor(m, 32, 64));
    if (slot == 0) agg[(size_t)node * C + c] = (end > beg) ? m : 0.0f;
}

// ---------------- weight pack: fragment-order bf16 hi/lo ----------------
// elem idx = ((t*8 + s)*64 + lane)*8 + j ;  n = t*16+(lane&15) ; k = s*32+(lane>>4)*8+j
__global__ void k_packw(const float* __restrict__ Wl, const float* __restrict__ Wr,
                        unsigned short* __restrict__ Wh, unsigned short* __restrict__ Wlo) {
    int idx = blockIdx.x * 256 + threadIdx.x;
    if (idx >= 128 * 256) return;
    int j = idx & 7, l = (idx >> 3) & 63, s = (idx >> 9) & 7, t = idx >> 12;
    int nrow = t * 16 + (l & 15);
    int k    = s * 32 + (l >> 4) * 8 + j;
    float v  = (k < 128) ? Wl[nrow * 128 + k] : Wr[nrow * 128 + (k - 128)];
    unsigned short h = f2bf(v);
    Wh[idx]  = h;
    Wlo[idx] = f2bf(v - bf2f(h));
}

// ---------------- LDS-staged split-bf16 MFMA SAGE gemm ----------------
// out[m,n] = relu( sum_k cat(A,X)[m,k]*Wcat[n,k] + b[n] ); HEAD: hout[m]=out[m,:]·hw + hb
template<int HEAD>
__global__ __launch_bounds__(256) void k_gemm_s(
        const float* __restrict__ A, const float* __restrict__ X,
        const unsigned short* __restrict__ Wh, const unsigned short* __restrict__ Wlo,
        const float* __restrict__ bias, float* __restrict__ out,
        const float* __restrict__ hw, const float* __restrict__ hb,
        float* __restrict__ hout, int n) {
    __shared__ __align__(16) unsigned short smw[2][8192];  // 2 x 16 slices x 512
    int tid  = threadIdx.x;
    int wave = tid >> 6, lane = tid & 63;
    int rit  = lane & 15, kgrp = lane >> 4;
    int m0   = blockIdx.x * 64 + wave * 16;
    int arow = m0 + rit; if (arow > n - 1) arow = n - 1;

    f32x4 acc[8];
    #pragma unroll
    for (int t = 0; t < 8; ++t) acc[t] = (f32x4){0.f, 0.f, 0.f, 0.f};

    // stage k-step s into LDS buffer b: 16 slices of 1KB, wave w does slices 4w..4w+3
    #define STAGE(s_, b_) do {                                                   \
        _Pragma("unroll")                                                        \
        for (int q = 0; q < 4; ++q) {                                            \
            int kk = wave * 4 + q;                                               \
            int tt = kk >> 1;                                                    \
            const unsigned short* g = ((kk & 1) ? Wlo : Wh)                      \
                                      + (((tt << 3) + (s_)) << 9) + (lane << 3); \
            gload_lds16(g, &smw[b_][kk << 9]);                                   \
        }                                                                        \
    } while (0)

    #define LOADA(s_, v0_, v1_) do {                                             \
        const float* p = ((s_) < 4 ? A + (size_t)arow * C + (s_) * 32            \
                                   : X + (size_t)arow * C + ((s_) - 4) * 32)     \
                         + kgrp * 8;                                             \
        v0_ = *(const float4*)p; v1_ = *(const float4*)(p + 4);                  \
    } while (0)

    float4 va0, va1, vb0, vb1;
    STAGE(0, 0);
    LOADA(0, va0, va1);
    __syncthreads();

    #pragma unroll
    for (int s = 0; s < 8; ++s) {
        if (s < 7) { STAGE(s + 1, (s + 1) & 1); LOADA(s + 1, vb0, vb1); }
        float fv[8] = {va0.x, va0.y, va0.z, va0.w, va1.x, va1.y, va1.z, va1.w};
        short8 a_hi, a_lo;
        #pragma unroll
        for (int j = 0; j < 8; ++j) {
            unsigned short h = f2bf(fv[j]);
            a_hi[j] = (short)h;
            a_lo[j] = (short)f2bf(fv[j] - bf2f(h));
        }
        const unsigned short* base = smw[s & 1];
        #pragma unroll
        for (int t = 0; t < 8; ++t) {
            short8 wh = *(const short8*)(base + ((t << 1) << 9)       + (lane << 3));
            short8 wl = *(const short8*)(base + ((((t << 1) | 1)) << 9) + (lane << 3));
            acc[t] = __builtin_amdgcn_mfma_f32_16x16x32_bf16(a_hi, wh, acc[t], 0, 0, 0);
            acc[t] = __builtin_amdgcn_mfma_f32_16x16x32_bf16(a_lo, wh, acc[t], 0, 0, 0);
            acc[t] = __builtin_amdgcn_mfma_f32_16x16x32_bf16(a_hi, wl, acc[t], 0, 0, 0);
        }
        if (s < 7) { va0 = vb0; va1 = vb1; __syncthreads(); }
    }
    #undef STAGE
    #undef LOADA

    // C/D: col = t*16 + rit, row = m0 + kgrp*4 + j
    if (HEAD) {
        float hs0 = 0.f, hs1 = 0.f, hs2 = 0.f, hs3 = 0.f;
        #pragma unroll
        for (int t = 0; t < 8; ++t) {
            int col = t * 16 + rit;
            float b = bias[col], w = hw[col];
            hs0 += fmaxf(acc[t][0] + b, 0.f) * w;
            hs1 += fmaxf(acc[t][1] + b, 0.f) * w;
            hs2 += fmaxf(acc[t][2] + b, 0.f) * w;
            hs3 += fmaxf(acc[t][3] + b, 0.f) * w;
        }
        #pragma unroll
        for (int msk = 1; msk < 16; msk <<= 1) {
            hs0 += __shfl_xor(hs0, msk, 64);
            hs1 += __shfl_xor(hs1, msk, 64);
            hs2 += __shfl_xor(hs2, msk, 64);
            hs3 += __shfl_xor(hs3, msk, 64);
        }
        if (rit == 0) {
            int r0 = m0 + kgrp * 4;
            float hbv = hb[0];
            if (r0     < n) hout[r0]     = hs0 + hbv;
            if (r0 + 1 < n) hout[r0 + 1] = hs1 + hbv;
            if (r0 + 2 < n) hout[r0 + 2] = hs2 + hbv;
            if (r0 + 3 < n) hout[r0 + 3] = hs3 + hbv;
        }
    } else {
        #pragma unroll
        for (int t = 0; t < 8; ++t) {
            int col = t * 16 + rit;
            float b = bias[col];
            #pragma unroll
            for (int j = 0; j < 4; ++j) {
                int rr = m0 + kgrp * 4 + j;
                if (rr < n) out[(size_t)rr * C + col] = fmaxf(acc[t][j] + b, 0.f);
            }
        }
    }
}

// ---------------- launch ----------------

extern "C" void kernel_launch(void* const* d_in, const int* in_sizes, int n_in,
                              void* d_out, int out_size, void* d_ws, size_t ws_size,
                              hipStream_t stream) {
    const float* x     = (const float*)d_in[0];
    const int*   ei    = (const int*)d_in[1];
    const int*   src   = ei;
    const int*   dstp  = ei + NE;
    const float* sWl   = (const float*)d_in[2];
    const float* sB    = (const float*)d_in[3];
    const float* sWr   = (const float*)d_in[4];
    const float* rt1Wl = (const float*)d_in[5];
    const float* rt1B  = (const float*)d_in[6];
    const float* rt1Wr = (const float*)d_in[7];
    const float* rt2Wl = (const float*)d_in[8];
    const float* rt2B  = (const float*)d_in[9];
    const float* rt2Wr = (const float*)d_in[10];
    const float* rt3W  = (const float*)d_in[11];
    const float* rt3B  = (const float*)d_in[12];
    const float* mv1Wl = (const float*)d_in[13];
    const float* mv1B  = (const float*)d_in[14];
    const float* mv1Wr = (const float*)d_in[15];
    const float* mv2Wl = (const float*)d_in[16];
    const float* mv2B  = (const float*)d_in[17];
    const float* mv2Wr = (const float*)d_in[18];
    const float* mv3W  = (const float*)d_in[19];
    const float* mv3B  = (const float*)d_in[20];
    float* out = (float*)d_out;

    char* ws = (char*)d_ws;
    int* rowptr = (int*)ws;                 // NN+1
    int* cursor = rowptr + (NN + 1);        // NN
    int* esrc   = cursor + NN;              // NE
    int* bsum   = esrc + NE;                // 64
    size_t off  = (((size_t)(NN + 1 + NN + NE + 64) * 4) + 255) & ~(size_t)255;
    float* bufA = (float*)(ws + off);
    float* buf1 = bufA + (size_t)NN * C;
    float* buf2 = buf1 + (size_t)NN * C;
    float* buf3 = buf2 + (size_t)NN * C;
    unsigned short* wpack = (unsigned short*)(buf3 + (size_t)NN * C);
    unsigned short* pk[5][2];
    for (int L = 0; L < 5; ++L) {
        pk[L][0] = wpack + (size_t)L * 65536;
        pk[L][1] = wpack + (size_t)L * 65536 + 32768;
    }

    const int TB = 256;
    const int NB = (NN + 1023) / 1024;

    // weight packing (independent of CSR build)
    k_packw<<<128, 256, 0, stream>>>(sWl,   sWr,   pk[0][0], pk[0][1]);
    k_packw<<<128, 256, 0, stream>>>(rt1Wl, rt1Wr, pk[1][0], pk[1][1]);
    k_packw<<<128, 256, 0, stream>>>(rt2Wl, rt2Wr, pk[2][0], pk[2][1]);
    k_packw<<<128, 256, 0, stream>>>(mv1Wl, mv1Wr, pk[3][0], pk[3][1]);
    k_packw<<<128, 256, 0, stream>>>(mv2Wl, mv2Wr, pk[4][0], pk[4][1]);

    // CSR build
    k_zero<<<(NN + TB - 1) / TB, TB, 0, stream>>>(cursor, NN);
    k_hist<<<(NE + TB - 1) / TB, TB, 0, stream>>>(dstp, cursor, NE);
    k_scan_blk<<<NB, 1024, 0, stream>>>(cursor, rowptr, bsum, NN);
    k_scan_sums<<<1, 64, 0, stream>>>(bsum, NB);
    k_scan_add<<<NB, 1024, 0, stream>>>(rowptr, bsum, NN);
    k_zero<<<(NN + TB - 1) / TB, TB, 0, stream>>>(cursor, NN);
    k_fill<<<(NE + TB - 1) / TB, TB, 0, stream>>>(src, dstp, rowptr, cursor, esrc, NE);

    dim3 gSeg((NN + 3) / 4, C / CT), bSeg(256);
    dim3 gGem((NN + 63) / 64), bGem(256);

    // shared layer: mv = relu(sage(x))
    k_segmax_w<<<gSeg, bSeg, 0, stream>>>(x, rowptr, esrc, bufA, NN);
    k_gemm_s<0><<<gGem, bGem, 0, stream>>>(bufA, x, pk[0][0], pk[0][1], sB, buf1,
                                           nullptr, nullptr, nullptr, NN);
    // agg(mv) shared by rt1 and mv1
    k_segmax_w<<<gSeg, bSeg, 0, stream>>>(buf1, rowptr, esrc, bufA, NN);
    k_gemm_s<0><<<gGem, bGem, 0, stream>>>(bufA, buf1, pk[1][0], pk[1][1], rt1B, buf2,
                                           nullptr, nullptr, nullptr, NN); // rt
    k_gemm_s<0><<<gGem, bGem, 0, stream>>>(bufA, buf1, pk[3][0], pk[3][1], mv1B, buf3,
                                           nullptr, nullptr, nullptr, NN); // md
    // rt branch layer 2 + fused rt3 head
    k_segmax_w<<<gSeg, bSeg, 0, stream>>>(buf2, rowptr, esrc, bufA, NN);
    k_gemm_s<1><<<gGem, bGem, 0, stream>>>(bufA, buf2, pk[2][0], pk[2][1], rt2B, nullptr,
                                           rt3W, rt3B, out, NN);
    // md branch layer 2 + fused mv3 head
    k_segmax_w<<<gSeg, bSeg, 0, stream>>>(buf3, rowptr, esrc, bufA, NN);
    k_gemm_s<1><<<gGem, bGem, 0, stream>>>(bufA, buf3, pk[4][0], pk[4][1], mv2B, nullptr,
                                           mv3W, mv3B, out + NN, NN);
}

// Round 5
// 474.445 us; speedup vs baseline: 1.5228x; 1.5228x over previous
//
#include <hip/hip_runtime.h>
#include <hip/hip_bf16.h>
#include <math.h>

#define NN 50000
#define NE 800000
#define C  128
typedef unsigned int u32;

using f32x4  = __attribute__((ext_vector_type(4))) float;
using short8 = __attribute__((ext_vector_type(8))) short;

__device__ __forceinline__ unsigned short f2bf(float f) {
    unsigned int u = __float_as_uint(f);
    unsigned int r = u + 0x7FFFu + ((u >> 16) & 1u);
    return (unsigned short)(r >> 16);
}
__device__ __forceinline__ float bf2f(unsigned short h) {
    return __uint_as_float(((unsigned int)h) << 16);
}

// global(per-lane src) -> LDS(uniform base, lane*16B), 16B per lane
__device__ __forceinline__ void gload_lds16(const unsigned short* g, unsigned short* l) {
    __builtin_amdgcn_global_load_lds(
        (const __attribute__((address_space(1))) u32*)g,
        (__attribute__((address_space(3))) u32*)l,
        16, 0, 0);
}

// ---------------- CSR build ----------------

__global__ void k_zero(int* __restrict__ p, int n) {
    int i = blockIdx.x * blockDim.x + threadIdx.x;
    if (i < n) p[i] = 0;
}

__global__ void k_hist(const int* __restrict__ dst, int* __restrict__ deg, int nE) {
    int e = blockIdx.x * blockDim.x + threadIdx.x;
    if (e < nE) atomicAdd(&deg[dst[e]], 1);
}

__global__ __launch_bounds__(1024) void k_scan_blk(const int* __restrict__ deg, int* __restrict__ rowptr,
                                                   int* __restrict__ bsum, int n) {
    __shared__ int wsum[16];
    int tid = threadIdx.x, lane = tid & 63, wid = tid >> 6;
    int i = blockIdx.x * 1024 + tid;
    int v = (i < n) ? deg[i] : 0;
    int incl = v;
    #pragma unroll
    for (int d = 1; d < 64; d <<= 1) {
        int t = __shfl_up(incl, d, 64);
        if (lane >= d) incl += t;
    }
    if (lane == 63) wsum[wid] = incl;
    __syncthreads();
    int wo = 0;
    #pragma unroll
    for (int w = 0; w < 16; ++w) wo += (w < wid) ? wsum[w] : 0;
    if (i < n) rowptr[i + 1] = wo + incl;
    if (tid == 1023) bsum[blockIdx.x] = wo + incl;
}

__global__ void k_scan_sums(int* __restrict__ bsum, int nb) {
    int lane = threadIdx.x;
    int v = (lane < nb) ? bsum[lane] : 0;
    int incl = v;
    #pragma unroll
    for (int d = 1; d < 64; d <<= 1) {
        int t = __shfl_up(incl, d, 64);
        if (lane >= d) incl += t;
    }
    if (lane < nb) bsum[lane] = incl - v;  // exclusive
}

__global__ __launch_bounds__(1024) void k_scan_add(int* __restrict__ rowptr, const int* __restrict__ bsum, int n) {
    int i = blockIdx.x * 1024 + threadIdx.x;
    if (i == 0) rowptr[0] = 0;
    if (i < n) rowptr[i + 1] += bsum[blockIdx.x];
}

__global__ void k_fill(const int* __restrict__ src, const int* __restrict__ dst,
                       const int* __restrict__ rowptr, int* __restrict__ cursor,
                       int* __restrict__ esrc, int nE) {
    int e = blockIdx.x * blockDim.x + threadIdx.x;
    if (e < nE) {
        int d   = dst[e];
        int pos = rowptr[d] + atomicAdd(&cursor[d], 1);
        esrc[pos] = src[e];
    }
}

// ---------------- segment max: full-channel, 2 nodes/block ----------------
// thread = channel (128), 8 gathers in flight per thread. NT store keeps the
// 25.6 MB agg write stream from evicting the gather's hot rows out of L2.
__global__ __launch_bounds__(256) void k_segmax(const float* __restrict__ h, const int* __restrict__ rowptr,
                                                const int* __restrict__ esrc, float* __restrict__ agg, int n) {
    int node = blockIdx.x * 2 + (threadIdx.x >> 7);
    int c    = threadIdx.x & 127;
    if (node >= n) return;
    int beg = rowptr[node], end = rowptr[node + 1];
    float m = -INFINITY;
    int i = beg;
    for (; i + 7 < end; i += 8) {
        int s0 = esrc[i],     s1 = esrc[i + 1], s2 = esrc[i + 2], s3 = esrc[i + 3];
        int s4 = esrc[i + 4], s5 = esrc[i + 5], s6 = esrc[i + 6], s7 = esrc[i + 7];
        float v0 = h[(size_t)s0 * C + c], v1 = h[(size_t)s1 * C + c];
        float v2 = h[(size_t)s2 * C + c], v3 = h[(size_t)s3 * C + c];
        float v4 = h[(size_t)s4 * C + c], v5 = h[(size_t)s5 * C + c];
        float v6 = h[(size_t)s6 * C + c], v7 = h[(size_t)s7 * C + c];
        m = fmaxf(m, fmaxf(fmaxf(fmaxf(v0, v1), fmaxf(v2, v3)),
                           fmaxf(fmaxf(v4, v5), fmaxf(v6, v7))));
    }
    for (; i < end; ++i) m = fmaxf(m, h[(size_t)esrc[i] * C + c]);
    float r = (end > beg) ? m : 0.0f;
    __builtin_nontemporal_store(r, &agg[(size_t)node * C + c]);
}

// ---------------- weight pack: fragment-order bf16 hi/lo ----------------
// elem idx = ((t*8 + s)*64 + lane)*8 + j ;  n = t*16+(lane&15) ; k = s*32+(lane>>4)*8+j
__global__ void k_packw(const float* __restrict__ Wl, const float* __restrict__ Wr,
                        unsigned short* __restrict__ Wh, unsigned short* __restrict__ Wlo) {
    int idx = blockIdx.x * 256 + threadIdx.x;
    if (idx >= 128 * 256) return;
    int j = idx & 7, l = (idx >> 3) & 63, s = (idx >> 9) & 7, t = idx >> 12;
    int nrow = t * 16 + (l & 15);
    int k    = s * 32 + (l >> 4) * 8 + j;
    float v  = (k < 128) ? Wl[nrow * 128 + k] : Wr[nrow * 128 + (k - 128)];
    unsigned short h = f2bf(v);
    Wh[idx]  = h;
    Wlo[idx] = f2bf(v - bf2f(h));
}

// ---------------- LDS-staged split-bf16 MFMA SAGE gemm ----------------
// out[m,n] = relu( sum_k cat(A,X)[m,k]*Wcat[n,k] + b[n] ); HEAD: hout[m]=out[m,:]·hw + hb
template<int HEAD>
__global__ __launch_bounds__(256) void k_gemm_s(
        const float* __restrict__ A, const float* __restrict__ X,
        const unsigned short* __restrict__ Wh, const unsigned short* __restrict__ Wlo,
        const float* __restrict__ bias, float* __restrict__ out,
        const float* __restrict__ hw, const float* __restrict__ hb,
        float* __restrict__ hout, int n) {
    __shared__ __align__(16) unsigned short smw[2][8192];  // 2 x 16 slices x 512
    int tid  = threadIdx.x;
    int wave = tid >> 6, lane = tid & 63;
    int rit  = lane & 15, kgrp = lane >> 4;
    int m0   = blockIdx.x * 64 + wave * 16;
    int arow = m0 + rit; if (arow > n - 1) arow = n - 1;

    f32x4 acc[8];
    #pragma unroll
    for (int t = 0; t < 8; ++t) acc[t] = (f32x4){0.f, 0.f, 0.f, 0.f};

    #define STAGE(s_, b_) do {                                                   \
        _Pragma("unroll")                                                        \
        for (int q = 0; q < 4; ++q) {                                            \
            int kk = wave * 4 + q;                                               \
            int tt = kk >> 1;                                                    \
            const unsigned short* g = ((kk & 1) ? Wlo : Wh)                      \
                                      + (((tt << 3) + (s_)) << 9) + (lane << 3); \
            gload_lds16(g, &smw[b_][kk << 9]);                                   \
        }                                                                        \
    } while (0)

    #define LOADA(s_, v0_, v1_) do {                                             \
        const float* p = ((s_) < 4 ? A + (size_t)arow * C + (s_) * 32            \
                                   : X + (size_t)arow * C + ((s_) - 4) * 32)     \
                         + kgrp * 8;                                             \
        v0_ = *(const float4*)p; v1_ = *(const float4*)(p + 4);                  \
    } while (0)

    float4 va0, va1, vb0, vb1;
    STAGE(0, 0);
    LOADA(0, va0, va1);
    __syncthreads();

    #pragma unroll
    for (int s = 0; s < 8; ++s) {
        if (s < 7) { STAGE(s + 1, (s + 1) & 1); LOADA(s + 1, vb0, vb1); }
        float fv[8] = {va0.x, va0.y, va0.z, va0.w, va1.x, va1.y, va1.z, va1.w};
        short8 a_hi, a_lo;
        #pragma unroll
        for (int j = 0; j < 8; ++j) {
            unsigned short h = f2bf(fv[j]);
            a_hi[j] = (short)h;
            a_lo[j] = (short)f2bf(fv[j] - bf2f(h));
        }
        const unsigned short* base = smw[s & 1];
        #pragma unroll
        for (int t = 0; t < 8; ++t) {
            short8 wh = *(const short8*)(base + ((t << 1) << 9)         + (lane << 3));
            short8 wl = *(const short8*)(base + ((((t << 1) | 1)) << 9) + (lane << 3));
            acc[t] = __builtin_amdgcn_mfma_f32_16x16x32_bf16(a_hi, wh, acc[t], 0, 0, 0);
            acc[t] = __builtin_amdgcn_mfma_f32_16x16x32_bf16(a_lo, wh, acc[t], 0, 0, 0);
            acc[t] = __builtin_amdgcn_mfma_f32_16x16x32_bf16(a_hi, wl, acc[t], 0, 0, 0);
        }
        if (s < 7) { va0 = vb0; va1 = vb1; __syncthreads(); }
    }
    #undef STAGE
    #undef LOADA

    // C/D: col = t*16 + rit, row = m0 + kgrp*4 + j
    if (HEAD) {
        float hs0 = 0.f, hs1 = 0.f, hs2 = 0.f, hs3 = 0.f;
        #pragma unroll
        for (int t = 0; t < 8; ++t) {
            int col = t * 16 + rit;
            float b = bias[col], w = hw[col];
            hs0 += fmaxf(acc[t][0] + b, 0.f) * w;
            hs1 += fmaxf(acc[t][1] + b, 0.f) * w;
            hs2 += fmaxf(acc[t][2] + b, 0.f) * w;
            hs3 += fmaxf(acc[t][3] + b, 0.f) * w;
        }
        #pragma unroll
        for (int msk = 1; msk < 16; msk <<= 1) {
            hs0 += __shfl_xor(hs0, msk, 64);
            hs1 += __shfl_xor(hs1, msk, 64);
            hs2 += __shfl_xor(hs2, msk, 64);
            hs3 += __shfl_xor(hs3, msk, 64);
        }
        if (rit == 0) {
            int r0 = m0 + kgrp * 4;
            float hbv = hb[0];
            if (r0     < n) hout[r0]     = hs0 + hbv;
            if (r0 + 1 < n) hout[r0 + 1] = hs1 + hbv;
            if (r0 + 2 < n) hout[r0 + 2] = hs2 + hbv;
            if (r0 + 3 < n) hout[r0 + 3] = hs3 + hbv;
        }
    } else {
        #pragma unroll
        for (int t = 0; t < 8; ++t) {
            int col = t * 16 + rit;
            float b = bias[col];
            #pragma unroll
            for (int j = 0; j < 4; ++j) {
                int rr = m0 + kgrp * 4 + j;
                if (rr < n) out[(size_t)rr * C + col] = fmaxf(acc[t][j] + b, 0.f);
            }
        }
    }
}

// ---------------- launch ----------------

extern "C" void kernel_launch(void* const* d_in, const int* in_sizes, int n_in,
                              void* d_out, int out_size, void* d_ws, size_t ws_size,
                              hipStream_t stream) {
    const float* x     = (const float*)d_in[0];
    const int*   ei    = (const int*)d_in[1];
    const int*   src   = ei;
    const int*   dstp  = ei + NE;
    const float* sWl   = (const float*)d_in[2];
    const float* sB    = (const float*)d_in[3];
    const float* sWr   = (const float*)d_in[4];
    const float* rt1Wl = (const float*)d_in[5];
    const float* rt1B  = (const float*)d_in[6];
    const float* rt1Wr = (const float*)d_in[7];
    const float* rt2Wl = (const float*)d_in[8];
    const float* rt2B  = (const float*)d_in[9];
    const float* rt2Wr = (const float*)d_in[10];
    const float* rt3W  = (const float*)d_in[11];
    const float* rt3B  = (const float*)d_in[12];
    const float* mv1Wl = (const float*)d_in[13];
    const float* mv1B  = (const float*)d_in[14];
    const float* mv1Wr = (const float*)d_in[15];
    const float* mv2Wl = (const float*)d_in[16];
    const float* mv2B  = (const float*)d_in[17];
    const float* mv2Wr = (const float*)d_in[18];
    const float* mv3W  = (const float*)d_in[19];
    const float* mv3B  = (const float*)d_in[20];
    float* out = (float*)d_out;

    char* ws = (char*)d_ws;
    int* rowptr = (int*)ws;                 // NN+1
    int* cursor = rowptr + (NN + 1);        // NN
    int* esrc   = cursor + NN;              // NE
    int* bsum   = esrc + NE;                // 64
    size_t off  = (((size_t)(NN + 1 + NN + NE + 64) * 4) + 255) & ~(size_t)255;
    float* bufA = (float*)(ws + off);
    float* buf1 = bufA + (size_t)NN * C;
    float* buf2 = buf1 + (size_t)NN * C;
    float* buf3 = buf2 + (size_t)NN * C;
    unsigned short* wpack = (unsigned short*)(buf3 + (size_t)NN * C);
    unsigned short* pk[5][2];
    for (int L = 0; L < 5; ++L) {
        pk[L][0] = wpack + (size_t)L * 65536;
        pk[L][1] = wpack + (size_t)L * 65536 + 32768;
    }

    const int TB = 256;
    const int NB = (NN + 1023) / 1024;

    // weight packing (independent of CSR build)
    k_packw<<<128, 256, 0, stream>>>(sWl,   sWr,   pk[0][0], pk[0][1]);
    k_packw<<<128, 256, 0, stream>>>(rt1Wl, rt1Wr, pk[1][0], pk[1][1]);
    k_packw<<<128, 256, 0, stream>>>(rt2Wl, rt2Wr, pk[2][0], pk[2][1]);
    k_packw<<<128, 256, 0, stream>>>(mv1Wl, mv1Wr, pk[3][0], pk[3][1]);
    k_packw<<<128, 256, 0, stream>>>(mv2Wl, mv2Wr, pk[4][0], pk[4][1]);

    // CSR build
    k_zero<<<(NN + TB - 1) / TB, TB, 0, stream>>>(cursor, NN);
    k_hist<<<(NE + TB - 1) / TB, TB, 0, stream>>>(dstp, cursor, NE);
    k_scan_blk<<<NB, 1024, 0, stream>>>(cursor, rowptr, bsum, NN);
    k_scan_sums<<<1, 64, 0, stream>>>(bsum, NB);
    k_scan_add<<<NB, 1024, 0, stream>>>(rowptr, bsum, NN);
    k_zero<<<(NN + TB - 1) / TB, TB, 0, stream>>>(cursor, NN);
    k_fill<<<(NE + TB - 1) / TB, TB, 0, stream>>>(src, dstp, rowptr, cursor, esrc, NE);

    dim3 gSeg(NN / 2), bSeg(256);
    dim3 gGem((NN + 63) / 64), bGem(256);

    // shared layer: mv = relu(sage(x))
    k_segmax<<<gSeg, bSeg, 0, stream>>>(x, rowptr, esrc, bufA, NN);
    k_gemm_s<0><<<gGem, bGem, 0, stream>>>(bufA, x, pk[0][0], pk[0][1], sB, buf1,
                                           nullptr, nullptr, nullptr, NN);
    // agg(mv) shared by rt1 and mv1
    k_segmax<<<gSeg, bSeg, 0, stream>>>(buf1, rowptr, esrc, bufA, NN);
    k_gemm_s<0><<<gGem, bGem, 0, stream>>>(bufA, buf1, pk[1][0], pk[1][1], rt1B, buf2,
                                           nullptr, nullptr, nullptr, NN); // rt
    k_gemm_s<0><<<gGem, bGem, 0, stream>>>(bufA, buf1, pk[3][0], pk[3][1], mv1B, buf3,
                                           nullptr, nullptr, nullptr, NN); // md
    // rt branch layer 2 + fused rt3 head
    k_segmax<<<gSeg, bSeg, 0, stream>>>(buf2, rowptr, esrc, bufA, NN);
    k_gemm_s<1><<<gGem, bGem, 0, stream>>>(bufA, buf2, pk[2][0], pk[2][1], rt2B, nullptr,
                                           rt3W, rt3B, out, NN);
    // md branch layer 2 + fused mv3 head
    k_segmax<<<gSeg, bSeg, 0, stream>>>(buf3, rowptr, esrc, bufA, NN);
    k_gemm_s<1><<<gGem, bGem, 0, stream>>>(bufA, buf3, pk[4][0], pk[4][1], mv2B, nullptr,
                                           mv3W, mv3B, out + NN, NN);
}

// Round 6
// 350.444 us; speedup vs baseline: 2.0616x; 1.3538x over previous
//
#include <hip/hip_runtime.h>
#include <hip/hip_bf16.h>
#include <math.h>

#define NN 50000
#define NE 800000
#define C  128
typedef unsigned int u32;

using f32x4  = __attribute__((ext_vector_type(4))) float;
using short8 = __attribute__((ext_vector_type(8))) short;

__device__ __forceinline__ unsigned short f2bf(float f) {
    unsigned int u = __float_as_uint(f);
    unsigned int r = u + 0x7FFFu + ((u >> 16) & 1u);
    return (unsigned short)(r >> 16);
}
__device__ __forceinline__ float bf2f(unsigned short h) {
    return __uint_as_float(((unsigned int)h) << 16);
}

// global(per-lane src) -> LDS(uniform base, lane*16B), 16B per lane
__device__ __forceinline__ void gload_lds16(const unsigned short* g, unsigned short* l) {
    __builtin_amdgcn_global_load_lds(
        (const __attribute__((address_space(1))) u32*)g,
        (__attribute__((address_space(3))) u32*)l,
        16, 0, 0);
}

// ---------------- CSR build ----------------

__global__ void k_zero(int* __restrict__ p, int n) {
    int i = blockIdx.x * blockDim.x + threadIdx.x;
    if (i < n) p[i] = 0;
}

__global__ void k_hist(const int* __restrict__ dst, int* __restrict__ deg, int nE) {
    int e = blockIdx.x * blockDim.x + threadIdx.x;
    if (e < nE) atomicAdd(&deg[dst[e]], 1);
}

__global__ __launch_bounds__(1024) void k_scan_blk(const int* __restrict__ deg, int* __restrict__ rowptr,
                                                   int* __restrict__ bsum, int n) {
    __shared__ int wsum[16];
    int tid = threadIdx.x, lane = tid & 63, wid = tid >> 6;
    int i = blockIdx.x * 1024 + tid;
    int v = (i < n) ? deg[i] : 0;
    int incl = v;
    #pragma unroll
    for (int d = 1; d < 64; d <<= 1) {
        int t = __shfl_up(incl, d, 64);
        if (lane >= d) incl += t;
    }
    if (lane == 63) wsum[wid] = incl;
    __syncthreads();
    int wo = 0;
    #pragma unroll
    for (int w = 0; w < 16; ++w) wo += (w < wid) ? wsum[w] : 0;
    if (i < n) rowptr[i + 1] = wo + incl;
    if (tid == 1023) bsum[blockIdx.x] = wo + incl;
}

__global__ void k_scan_sums(int* __restrict__ bsum, int nb) {
    int lane = threadIdx.x;
    int v = (lane < nb) ? bsum[lane] : 0;
    int incl = v;
    #pragma unroll
    for (int d = 1; d < 64; d <<= 1) {
        int t = __shfl_up(incl, d, 64);
        if (lane >= d) incl += t;
    }
    if (lane < nb) bsum[lane] = incl - v;  // exclusive
}

__global__ __launch_bounds__(1024) void k_scan_add(int* __restrict__ rowptr, const int* __restrict__ bsum, int n) {
    int i = blockIdx.x * 1024 + threadIdx.x;
    if (i == 0) rowptr[0] = 0;
    if (i < n) rowptr[i + 1] += bsum[blockIdx.x];
}

// esrc stores src*64 (row offset in u32 units of the packed-bf16 feature array)
__global__ void k_fill(const int* __restrict__ src, const int* __restrict__ dst,
                       const int* __restrict__ rowptr, int* __restrict__ cursor,
                       int* __restrict__ esrc, int nE) {
    int e = blockIdx.x * blockDim.x + threadIdx.x;
    if (e < nE) {
        int d   = dst[e];
        int pos = rowptr[d] + atomicAdd(&cursor[d], 1);
        esrc[pos] = src[e] << 6;
    }
}

// ---------------- fp32 -> packed bf16 convert (for x) ----------------
__global__ void k_cvt(const float* __restrict__ in, u32* __restrict__ outp, int n64) {
    int i = blockIdx.x * 256 + threadIdx.x;
    if (i < n64) {
        float2 v = *(const float2*)(in + (size_t)i * 2);
        outp[i] = ((u32)f2bf(v.x)) | (((u32)f2bf(v.y)) << 16);
    }
}

// ---------------- segment max over packed bf16: wave per node ----------------
// row = 64 lanes x u32 (2 channels each) = 256 B = 2 cache lines. 8 edges in flight.
#define UPK(w_) { mlo = fmaxf(mlo, __uint_as_float((w_) << 16)); \
                  mhi = fmaxf(mhi, __uint_as_float((w_) & 0xFFFF0000u)); }
__global__ __launch_bounds__(256) void k_segmax_bf(const u32* __restrict__ h2, const int* __restrict__ rowptr,
                                                   const int* __restrict__ esrc, u32* __restrict__ agg2, int n) {
    int node = blockIdx.x * 4 + (threadIdx.x >> 6);
    int lane = threadIdx.x & 63;
    if (node >= n) return;
    int beg = rowptr[node], end = rowptr[node + 1];
    float mlo = -INFINITY, mhi = -INFINITY;
    int i = beg;
    for (; i + 7 < end; i += 8) {
        u32 w0 = h2[(size_t)esrc[i]     + lane];
        u32 w1 = h2[(size_t)esrc[i + 1] + lane];
        u32 w2 = h2[(size_t)esrc[i + 2] + lane];
        u32 w3 = h2[(size_t)esrc[i + 3] + lane];
        u32 w4 = h2[(size_t)esrc[i + 4] + lane];
        u32 w5 = h2[(size_t)esrc[i + 5] + lane];
        u32 w6 = h2[(size_t)esrc[i + 6] + lane];
        u32 w7 = h2[(size_t)esrc[i + 7] + lane];
        UPK(w0) UPK(w1) UPK(w2) UPK(w3) UPK(w4) UPK(w5) UPK(w6) UPK(w7)
    }
    for (; i < end; ++i) { u32 w = h2[(size_t)esrc[i] + lane]; UPK(w) }
    u32 r = 0u;  // empty segment -> 0 per isfinite() rule
    if (end > beg)
        r = (__float_as_uint(mlo) >> 16) | (__float_as_uint(mhi) & 0xFFFF0000u);  // exact repack
    __builtin_nontemporal_store(r, &agg2[(size_t)node * 64 + lane]);
}

// ---------------- weight pack: fragment-order bf16 hi/lo ----------------
// elem idx = ((t*8 + s)*64 + lane)*8 + j ;  n = t*16+(lane&15) ; k = s*32+(lane>>4)*8+j
__global__ void k_packw(const float* __restrict__ Wl, const float* __restrict__ Wr,
                        unsigned short* __restrict__ Wh, unsigned short* __restrict__ Wlo) {
    int idx = blockIdx.x * 256 + threadIdx.x;
    if (idx >= 128 * 256) return;
    int j = idx & 7, l = (idx >> 3) & 63, s = (idx >> 9) & 7, t = idx >> 12;
    int nrow = t * 16 + (l & 15);
    int k    = s * 32 + (l >> 4) * 8 + j;
    float v  = (k < 128) ? Wl[nrow * 128 + k] : Wr[nrow * 128 + (k - 128)];
    unsigned short h = f2bf(v);
    Wh[idx]  = h;
    Wlo[idx] = f2bf(v - bf2f(h));
}

// ---------------- LDS-staged split-bf16 MFMA SAGE gemm ----------------
// A (agg) is exact bf16: 2 MFMAs per (s<4,t). X is fp32, split hi/lo: 3 MFMAs.
// out fp32 (next GEMM's X) + outbf packed bf16 (next gather). HEAD: fused 128->1 dot.
template<int HEAD>
__global__ __launch_bounds__(256) void k_gemm_s(
        const unsigned short* __restrict__ Abf, const float* __restrict__ X,
        const unsigned short* __restrict__ Wh, const unsigned short* __restrict__ Wlo,
        const float* __restrict__ bias, float* __restrict__ out, u32* __restrict__ outbf,
        const float* __restrict__ hw, const float* __restrict__ hb,
        float* __restrict__ hout, int n) {
    __shared__ __align__(16) unsigned short smw[2][8192];  // 2 x 16 slices x 512
    int tid  = threadIdx.x;
    int wave = tid >> 6, lane = tid & 63;
    int rit  = lane & 15, kgrp = lane >> 4;
    int m0   = blockIdx.x * 64 + wave * 16;
    int arow = m0 + rit; if (arow > n - 1) arow = n - 1;

    f32x4 acc[8];
    #pragma unroll
    for (int t = 0; t < 8; ++t) acc[t] = (f32x4){0.f, 0.f, 0.f, 0.f};

    #define STAGE(s_, b_) do {                                                   \
        _Pragma("unroll")                                                        \
        for (int q = 0; q < 4; ++q) {                                            \
            int kk = wave * 4 + q;                                               \
            int tt = kk >> 1;                                                    \
            const unsigned short* g = ((kk & 1) ? Wlo : Wh)                      \
                                      + (((tt << 3) + (s_)) << 9) + (lane << 3); \
            gload_lds16(g, &smw[b_][kk << 9]);                                   \
        }                                                                        \
    } while (0)

    short8 a_cur, a_nxt;
    float4 xv0, xv1, xn0, xn1;
    STAGE(0, 0);
    a_cur = *(const short8*)(Abf + (size_t)arow * C + kgrp * 8);
    __syncthreads();

    #pragma unroll
    for (int s = 0; s < 8; ++s) {
        if (s < 7) {
            STAGE(s + 1, (s + 1) & 1);
            if (s + 1 < 4) {
                a_nxt = *(const short8*)(Abf + (size_t)arow * C + (s + 1) * 32 + kgrp * 8);
            } else {
                const float* p = X + (size_t)arow * C + (s + 1 - 4) * 32 + kgrp * 8;
                xn0 = *(const float4*)p; xn1 = *(const float4*)(p + 4);
            }
        }
        const unsigned short* base = smw[s & 1];
        if (s < 4) {
            #pragma unroll
            for (int t = 0; t < 8; ++t) {
                short8 wh = *(const short8*)(base + ((t << 1) << 9)         + (lane << 3));
                short8 wl = *(const short8*)(base + ((((t << 1) | 1)) << 9) + (lane << 3));
                acc[t] = __builtin_amdgcn_mfma_f32_16x16x32_bf16(a_cur, wh, acc[t], 0, 0, 0);
                acc[t] = __builtin_amdgcn_mfma_f32_16x16x32_bf16(a_cur, wl, acc[t], 0, 0, 0);
            }
        } else {
            float fv[8] = {xv0.x, xv0.y, xv0.z, xv0.w, xv1.x, xv1.y, xv1.z, xv1.w};
            short8 a_hi, a_lo;
            #pragma unroll
            for (int j = 0; j < 8; ++j) {
                unsigned short h = f2bf(fv[j]);
                a_hi[j] = (short)h;
                a_lo[j] = (short)f2bf(fv[j] - bf2f(h));
            }
            #pragma unroll
            for (int t = 0; t < 8; ++t) {
                short8 wh = *(const short8*)(base + ((t << 1) << 9)         + (lane << 3));
                short8 wl = *(const short8*)(base + ((((t << 1) | 1)) << 9) + (lane << 3));
                acc[t] = __builtin_amdgcn_mfma_f32_16x16x32_bf16(a_hi, wh, acc[t], 0, 0, 0);
                acc[t] = __builtin_amdgcn_mfma_f32_16x16x32_bf16(a_lo, wh, acc[t], 0, 0, 0);
                acc[t] = __builtin_amdgcn_mfma_f32_16x16x32_bf16(a_hi, wl, acc[t], 0, 0, 0);
            }
        }
        if (s < 7) {
            if (s + 1 < 4) a_cur = a_nxt; else { xv0 = xn0; xv1 = xn1; }
            __syncthreads();
        }
    }
    #undef STAGE

    // C/D: col = t*16 + rit, row = m0 + kgrp*4 + j
    if (HEAD) {
        float hs0 = 0.f, hs1 = 0.f, hs2 = 0.f, hs3 = 0.f;
        #pragma unroll
        for (int t = 0; t < 8; ++t) {
            int col = t * 16 + rit;
            float b = bias[col], w = hw[col];
            hs0 += fmaxf(acc[t][0] + b, 0.f) * w;
            hs1 += fmaxf(acc[t][1] + b, 0.f) * w;
            hs2 += fmaxf(acc[t][2] + b, 0.f) * w;
            hs3 += fmaxf(acc[t][3] + b, 0.f) * w;
        }
        #pragma unroll
        for (int msk = 1; msk < 16; msk <<= 1) {
            hs0 += __shfl_xor(hs0, msk, 64);
            hs1 += __shfl_xor(hs1, msk, 64);
            hs2 += __shfl_xor(hs2, msk, 64);
            hs3 += __shfl_xor(hs3, msk, 64);
        }
        if (rit == 0) {
            int r0 = m0 + kgrp * 4;
            float hbv = hb[0];
            if (r0     < n) hout[r0]     = hs0 + hbv;
            if (r0 + 1 < n) hout[r0 + 1] = hs1 + hbv;
            if (r0 + 2 < n) hout[r0 + 2] = hs2 + hbv;
            if (r0 + 3 < n) hout[r0 + 3] = hs3 + hbv;
        }
    } else {
        #pragma unroll
        for (int t = 0; t < 8; ++t) {
            int col = t * 16 + rit;
            float b = bias[col];
            #pragma unroll
            for (int j = 0; j < 4; ++j) {
                int rr = m0 + kgrp * 4 + j;
                float v = fmaxf(acc[t][j] + b, 0.f);
                if (rr < n) out[(size_t)rr * C + col] = v;
                float pv = __shfl_xor(v, 1, 64);  // partner col^1 (all lanes active)
                if (!(rit & 1) && rr < n) {
                    u32 pkd = ((u32)f2bf(v)) | (((u32)f2bf(pv)) << 16);
                    outbf[(size_t)rr * 64 + (col >> 1)] = pkd;
                }
            }
        }
    }
}

// ---------------- launch ----------------

extern "C" void kernel_launch(void* const* d_in, const int* in_sizes, int n_in,
                              void* d_out, int out_size, void* d_ws, size_t ws_size,
                              hipStream_t stream) {
    const float* x     = (const float*)d_in[0];
    const int*   ei    = (const int*)d_in[1];
    const int*   src   = ei;
    const int*   dstp  = ei + NE;
    const float* sWl   = (const float*)d_in[2];
    const float* sB    = (const float*)d_in[3];
    const float* sWr   = (const float*)d_in[4];
    const float* rt1Wl = (const float*)d_in[5];
    const float* rt1B  = (const float*)d_in[6];
    const float* rt1Wr = (const float*)d_in[7];
    const float* rt2Wl = (const float*)d_in[8];
    const float* rt2B  = (const float*)d_in[9];
    const float* rt2Wr = (const float*)d_in[10];
    const float* rt3W  = (const float*)d_in[11];
    const float* rt3B  = (const float*)d_in[12];
    const float* mv1Wl = (const float*)d_in[13];
    const float* mv1B  = (const float*)d_in[14];
    const float* mv1Wr = (const float*)d_in[15];
    const float* mv2Wl = (const float*)d_in[16];
    const float* mv2B  = (const float*)d_in[17];
    const float* mv2Wr = (const float*)d_in[18];
    const float* mv3W  = (const float*)d_in[19];
    const float* mv3B  = (const float*)d_in[20];
    float* out = (float*)d_out;

    char* ws = (char*)d_ws;
    int* rowptr = (int*)ws;                 // NN+1
    int* cursor = rowptr + (NN + 1);        // NN
    int* esrc   = cursor + NN;              // NE (pre-scaled src*64)
    int* bsum   = esrc + NE;                // 64
    size_t off  = (((size_t)(NN + 1 + NN + NE + 64) * 4) + 255) & ~(size_t)255;
    float* buf1 = (float*)(ws + off);       // fp32 layer outputs
    float* buf2 = buf1 + (size_t)NN * C;
    float* buf3 = buf2 + (size_t)NN * C;
    u32* aggbf  = (u32*)(buf3 + (size_t)NN * C);   // bf16 agg (NN*64 u32)
    u32* bf12   = aggbf + (size_t)NN * 64;         // bf16 copy: mv, then rt (lifetimes disjoint)
    u32* bf3    = bf12 + (size_t)NN * 64;          // bf16 copy: md
    u32* xbf    = (u32*)buf3;                      // alias: xbf dead before buf3 written
    unsigned short* wpack = (unsigned short*)(bf3 + (size_t)NN * 64);
    unsigned short* pk[5][2];
    for (int L = 0; L < 5; ++L) {
        pk[L][0] = wpack + (size_t)L * 65536;
        pk[L][1] = wpack + (size_t)L * 65536 + 32768;
    }

    const int TB = 256;
    const int NB = (NN + 1023) / 1024;

    // weight packing + x conversion (independent of CSR build)
    k_packw<<<128, 256, 0, stream>>>(sWl,   sWr,   pk[0][0], pk[0][1]);
    k_packw<<<128, 256, 0, stream>>>(rt1Wl, rt1Wr, pk[1][0], pk[1][1]);
    k_packw<<<128, 256, 0, stream>>>(rt2Wl, rt2Wr, pk[2][0], pk[2][1]);
    k_packw<<<128, 256, 0, stream>>>(mv1Wl, mv1Wr, pk[3][0], pk[3][1]);
    k_packw<<<128, 256, 0, stream>>>(mv2Wl, mv2Wr, pk[4][0], pk[4][1]);
    k_cvt<<<(NN * 64 + 255) / 256, 256, 0, stream>>>(x, xbf, NN * 64);

    // CSR build
    k_zero<<<(NN + TB - 1) / TB, TB, 0, stream>>>(cursor, NN);
    k_hist<<<(NE + TB - 1) / TB, TB, 0, stream>>>(dstp, cursor, NE);
    k_scan_blk<<<NB, 1024, 0, stream>>>(cursor, rowptr, bsum, NN);
    k_scan_sums<<<1, 64, 0, stream>>>(bsum, NB);
    k_scan_add<<<NB, 1024, 0, stream>>>(rowptr, bsum, NN);
    k_zero<<<(NN + TB - 1) / TB, TB, 0, stream>>>(cursor, NN);
    k_fill<<<(NE + TB - 1) / TB, TB, 0, stream>>>(src, dstp, rowptr, cursor, esrc, NE);

    dim3 gSeg((NN + 3) / 4), bSeg(256);
    dim3 gGem((NN + 63) / 64), bGem(256);

    // shared layer: mv = relu(sage(x))
    k_segmax_bf<<<gSeg, bSeg, 0, stream>>>(xbf, rowptr, esrc, aggbf, NN);
    k_gemm_s<0><<<gGem, bGem, 0, stream>>>((const unsigned short*)aggbf, x, pk[0][0], pk[0][1],
                                           sB, buf1, bf12, nullptr, nullptr, nullptr, NN);
    // agg(mv) shared by rt1 and mv1
    k_segmax_bf<<<gSeg, bSeg, 0, stream>>>(bf12, rowptr, esrc, aggbf, NN);
    k_gemm_s<0><<<gGem, bGem, 0, stream>>>((const unsigned short*)aggbf, buf1, pk[1][0], pk[1][1],
                                           rt1B, buf2, bf12, nullptr, nullptr, nullptr, NN); // rt (bf12 reused)
    k_gemm_s<0><<<gGem, bGem, 0, stream>>>((const unsigned short*)aggbf, buf1, pk[3][0], pk[3][1],
                                           mv1B, buf3, bf3, nullptr, nullptr, nullptr, NN);  // md
    // rt branch layer 2 + fused rt3 head
    k_segmax_bf<<<gSeg, bSeg, 0, stream>>>(bf12, rowptr, esrc, aggbf, NN);
    k_gemm_s<1><<<gGem, bGem, 0, stream>>>((const unsigned short*)aggbf, buf2, pk[2][0], pk[2][1],
                                           rt2B, nullptr, nullptr, rt3W, rt3B, out, NN);
    // md branch layer 2 + fused mv3 head
    k_segmax_bf<<<gSeg, bSeg, 0, stream>>>(bf3, rowptr, esrc, aggbf, NN);
    k_gemm_s<1><<<gGem, bGem, 0, stream>>>((const unsigned short*)aggbf, buf3, pk[4][0], pk[4][1],
                                           mv2B, nullptr, nullptr, mv3W, mv3B, out + NN, NN);
}

// Round 7
// 333.261 us; speedup vs baseline: 2.1679x; 1.0516x over previous
//
#include <hip/hip_runtime.h>
#include <hip/hip_bf16.h>
#include <math.h>

#define NN 50000
#define NE 800000
#define C  128
#define NR 8            // dst ranges (XCD-affine via blockIdx%8 heuristic)
#define RNG (NN / NR)   // 6250 nodes per range
typedef unsigned int u32;
typedef unsigned short u16;

using f32x4  = __attribute__((ext_vector_type(4))) float;
using short8 = __attribute__((ext_vector_type(8))) short;

__device__ __forceinline__ u16 f2bf(float f) {
    u32 u = __float_as_uint(f);
    u32 r = u + 0x7FFFu + ((u >> 16) & 1u);
    return (u16)(r >> 16);
}
__device__ __forceinline__ float bf2f(u16 h) {
    return __uint_as_float(((u32)h) << 16);
}

__device__ __forceinline__ void gload_lds16(const u16* g, u16* l) {
    __builtin_amdgcn_global_load_lds(
        (const __attribute__((address_space(1))) u32*)g,
        (__attribute__((address_space(3))) u32*)l,
        16, 0, 0);
}

// ---------------- CSR build ----------------

__global__ void k_zero(int* __restrict__ p, int n) {
    int i = blockIdx.x * blockDim.x + threadIdx.x;
    if (i < n) p[i] = 0;
}

// range-partitioned histogram: block handles chunk (bid>>3), dst range (bid&7).
__global__ __launch_bounds__(256) void k_hist_x(const int* __restrict__ dst, int* __restrict__ deg, int nE) {
    int r    = blockIdx.x & (NR - 1);
    int base = (blockIdx.x >> 3) * 4096;
    int lo   = r * RNG, hi = lo + RNG;
    #pragma unroll
    for (int it = 0; it < 16; ++it) {
        int e = base + it * 256 + threadIdx.x;
        if (e < nE) {
            int d = dst[e];
            if (d >= lo && d < hi) atomicAdd(&deg[d], 1);
        }
    }
}

__global__ __launch_bounds__(1024) void k_scan_blk(const int* __restrict__ deg, int* __restrict__ rowptr,
                                                   int* __restrict__ bsum, int n) {
    __shared__ int wsum[16];
    int tid = threadIdx.x, lane = tid & 63, wid = tid >> 6;
    int i = blockIdx.x * 1024 + tid;
    int v = (i < n) ? deg[i] : 0;
    int incl = v;
    #pragma unroll
    for (int d = 1; d < 64; d <<= 1) {
        int t = __shfl_up(incl, d, 64);
        if (lane >= d) incl += t;
    }
    if (lane == 63) wsum[wid] = incl;
    __syncthreads();
    int wo = 0;
    #pragma unroll
    for (int w = 0; w < 16; ++w) wo += (w < wid) ? wsum[w] : 0;
    if (i < n) rowptr[i + 1] = wo + incl;
    if (tid == 1023) bsum[blockIdx.x] = wo + incl;
}

__global__ void k_scan_sums(int* __restrict__ bsum, int nb) {
    int lane = threadIdx.x;
    int v = (lane < nb) ? bsum[lane] : 0;
    int incl = v;
    #pragma unroll
    for (int d = 1; d < 64; d <<= 1) {
        int t = __shfl_up(incl, d, 64);
        if (lane >= d) incl += t;
    }
    if (lane < nb) bsum[lane] = incl - v;  // exclusive
}

__global__ __launch_bounds__(1024) void k_scan_add(int* __restrict__ rowptr, const int* __restrict__ bsum, int n) {
    int i = blockIdx.x * 1024 + threadIdx.x;
    if (i == 0) rowptr[0] = 0;
    if (i < n) rowptr[i + 1] += bsum[blockIdx.x];
}

// range-partitioned fill: slot via atomicSub(deg) (consumes deg), u16 payload.
__global__ __launch_bounds__(256) void k_fill_x(const int* __restrict__ src, const int* __restrict__ dst,
                                                const int* __restrict__ rowptr, int* __restrict__ deg,
                                                u16* __restrict__ esrc, int nE) {
    int r    = blockIdx.x & (NR - 1);
    int base = (blockIdx.x >> 3) * 4096;
    int lo   = r * RNG, hi = lo + RNG;
    #pragma unroll
    for (int it = 0; it < 16; ++it) {
        int e = base + it * 256 + threadIdx.x;
        if (e < nE) {
            int d = dst[e];
            if (d >= lo && d < hi) {
                int old = atomicSub(&deg[d], 1);
                esrc[rowptr[d + 1] - old] = (u16)src[e];
            }
        }
    }
}

// ---------------- fp32 -> packed bf16 convert (for x) ----------------
__global__ void k_cvt(const float* __restrict__ in, u32* __restrict__ outp, int n64) {
    int i = blockIdx.x * 256 + threadIdx.x;
    if (i < n64) {
        float2 v = *(const float2*)(in + (size_t)i * 2);
        outp[i] = ((u32)f2bf(v.x)) | (((u32)f2bf(v.y)) << 16);
    }
}

// ---------------- segment max over packed bf16 ----------------
#define UPK(w_, lo_, hi_) { lo_ = fmaxf(lo_, __uint_as_float((w_) << 16)); \
                            hi_ = fmaxf(hi_, __uint_as_float((w_) & 0xFFFF0000u)); }

__global__ __launch_bounds__(256) void k_segmax_bf(const u32* __restrict__ h2, const int* __restrict__ rowptr,
                                                   const u16* __restrict__ esrc, u32* __restrict__ agg2, int n) {
    int node = blockIdx.x * 4 + (threadIdx.x >> 6);
    int lane = threadIdx.x & 63;
    if (node >= n) return;
    int beg = rowptr[node], end = rowptr[node + 1];
    float mlo = -INFINITY, mhi = -INFINITY;
    int i = beg;
    for (; i + 7 < end; i += 8) {
        u32 w0 = h2[((size_t)esrc[i]     << 6) + lane];
        u32 w1 = h2[((size_t)esrc[i + 1] << 6) + lane];
        u32 w2 = h2[((size_t)esrc[i + 2] << 6) + lane];
        u32 w3 = h2[((size_t)esrc[i + 3] << 6) + lane];
        u32 w4 = h2[((size_t)esrc[i + 4] << 6) + lane];
        u32 w5 = h2[((size_t)esrc[i + 5] << 6) + lane];
        u32 w6 = h2[((size_t)esrc[i + 6] << 6) + lane];
        u32 w7 = h2[((size_t)esrc[i + 7] << 6) + lane];
        UPK(w0, mlo, mhi) UPK(w1, mlo, mhi) UPK(w2, mlo, mhi) UPK(w3, mlo, mhi)
        UPK(w4, mlo, mhi) UPK(w5, mlo, mhi) UPK(w6, mlo, mhi) UPK(w7, mlo, mhi)
    }
    for (; i < end; ++i) { u32 w = h2[((size_t)esrc[i] << 6) + lane]; UPK(w, mlo, mhi) }
    u32 r = 0u;
    if (end > beg)
        r = (__float_as_uint(mlo) >> 16) | (__float_as_uint(mhi) & 0xFFFF0000u);
    __builtin_nontemporal_store(r, &agg2[(size_t)node * 64 + lane]);
}

// dual: aggregate two feature arrays over the same edge structure in one pass
__global__ __launch_bounds__(256) void k_segmax_bf2(const u32* __restrict__ hA, const u32* __restrict__ hB,
                                                    const int* __restrict__ rowptr, const u16* __restrict__ esrc,
                                                    u32* __restrict__ aggA, u32* __restrict__ aggB, int n) {
    int node = blockIdx.x * 4 + (threadIdx.x >> 6);
    int lane = threadIdx.x & 63;
    if (node >= n) return;
    int beg = rowptr[node], end = rowptr[node + 1];
    float alo = -INFINITY, ahi = -INFINITY, blo = -INFINITY, bhi = -INFINITY;
    int i = beg;
    for (; i + 3 < end; i += 4) {
        size_t b0 = ((size_t)esrc[i]     << 6) + lane;
        size_t b1 = ((size_t)esrc[i + 1] << 6) + lane;
        size_t b2 = ((size_t)esrc[i + 2] << 6) + lane;
        size_t b3 = ((size_t)esrc[i + 3] << 6) + lane;
        u32 a0 = hA[b0], a1 = hA[b1], a2 = hA[b2], a3 = hA[b3];
        u32 q0 = hB[b0], q1 = hB[b1], q2 = hB[b2], q3 = hB[b3];
        UPK(a0, alo, ahi) UPK(a1, alo, ahi) UPK(a2, alo, ahi) UPK(a3, alo, ahi)
        UPK(q0, blo, bhi) UPK(q1, blo, bhi) UPK(q2, blo, bhi) UPK(q3, blo, bhi)
    }
    for (; i < end; ++i) {
        size_t b = ((size_t)esrc[i] << 6) + lane;
        u32 a = hA[b], q = hB[b];
        UPK(a, alo, ahi) UPK(q, blo, bhi)
    }
    u32 ra = 0u, rb = 0u;
    if (end > beg) {
        ra = (__float_as_uint(alo) >> 16) | (__float_as_uint(ahi) & 0xFFFF0000u);
        rb = (__float_as_uint(blo) >> 16) | (__float_as_uint(bhi) & 0xFFFF0000u);
    }
    __builtin_nontemporal_store(ra, &aggA[(size_t)node * 64 + lane]);
    __builtin_nontemporal_store(rb, &aggB[(size_t)node * 64 + lane]);
}

// ---------------- weight pack: fragment-order bf16 hi/lo ----------------
__global__ void k_packw(const float* __restrict__ Wl, const float* __restrict__ Wr,
                        u16* __restrict__ Wh, u16* __restrict__ Wlo) {
    int idx = blockIdx.x * 256 + threadIdx.x;
    if (idx >= 128 * 256) return;
    int j = idx & 7, l = (idx >> 3) & 63, s = (idx >> 9) & 7, t = idx >> 12;
    int nrow = t * 16 + (l & 15);
    int k    = s * 32 + (l >> 4) * 8 + j;
    float v  = (k < 128) ? Wl[nrow * 128 + k] : Wr[nrow * 128 + (k - 128)];
    u16 h = f2bf(v);
    Wh[idx]  = h;
    Wlo[idx] = f2bf(v - bf2f(h));
}

// ---------------- LDS-staged split-bf16 MFMA SAGE gemm ----------------
template<int HEAD>
__global__ __launch_bounds__(256) void k_gemm_s(
        const u16* __restrict__ Abf, const float* __restrict__ X,
        const u16* __restrict__ Wh, const u16* __restrict__ Wlo,
        const float* __restrict__ bias, float* __restrict__ out, u32* __restrict__ outbf,
        const float* __restrict__ hw, const float* __restrict__ hb,
        float* __restrict__ hout, int n) {
    __shared__ __align__(16) u16 smw[2][8192];
    int tid  = threadIdx.x;
    int wave = tid >> 6, lane = tid & 63;
    int rit  = lane & 15, kgrp = lane >> 4;
    int m0   = blockIdx.x * 64 + wave * 16;
    int arow = m0 + rit; if (arow > n - 1) arow = n - 1;

    f32x4 acc[8];
    #pragma unroll
    for (int t = 0; t < 8; ++t) acc[t] = (f32x4){0.f, 0.f, 0.f, 0.f};

    #define STAGE(s_, b_) do {                                                   \
        _Pragma("unroll")                                                        \
        for (int q = 0; q < 4; ++q) {                                            \
            int kk = wave * 4 + q;                                               \
            int tt = kk >> 1;                                                    \
            const u16* g = ((kk & 1) ? Wlo : Wh)                                 \
                           + (((tt << 3) + (s_)) << 9) + (lane << 3);            \
            gload_lds16(g, &smw[b_][kk << 9]);                                   \
        }                                                                        \
    } while (0)

    short8 a_cur, a_nxt;
    float4 xv0, xv1, xn0, xn1;
    STAGE(0, 0);
    a_cur = *(const short8*)(Abf + (size_t)arow * C + kgrp * 8);
    __syncthreads();

    #pragma unroll
    for (int s = 0; s < 8; ++s) {
        if (s < 7) {
            STAGE(s + 1, (s + 1) & 1);
            if (s + 1 < 4) {
                a_nxt = *(const short8*)(Abf + (size_t)arow * C + (s + 1) * 32 + kgrp * 8);
            } else {
                const float* p = X + (size_t)arow * C + (s + 1 - 4) * 32 + kgrp * 8;
                xn0 = *(const float4*)p; xn1 = *(const float4*)(p + 4);
            }
        }
        const u16* base = smw[s & 1];
        if (s < 4) {
            #pragma unroll
            for (int t = 0; t < 8; ++t) {
                short8 wh = *(const short8*)(base + ((t << 1) << 9)         + (lane << 3));
                short8 wl = *(const short8*)(base + ((((t << 1) | 1)) << 9) + (lane << 3));
                acc[t] = __builtin_amdgcn_mfma_f32_16x16x32_bf16(a_cur, wh, acc[t], 0, 0, 0);
                acc[t] = __builtin_amdgcn_mfma_f32_16x16x32_bf16(a_cur, wl, acc[t], 0, 0, 0);
            }
        } else {
            float fv[8] = {xv0.x, xv0.y, xv0.z, xv0.w, xv1.x, xv1.y, xv1.z, xv1.w};
            short8 a_hi, a_lo;
            #pragma unroll
            for (int j = 0; j < 8; ++j) {
                u16 h = f2bf(fv[j]);
                a_hi[j] = (short)h;
                a_lo[j] = (short)f2bf(fv[j] - bf2f(h));
            }
            #pragma unroll
            for (int t = 0; t < 8; ++t) {
                short8 wh = *(const short8*)(base + ((t << 1) << 9)         + (lane << 3));
                short8 wl = *(const short8*)(base + ((((t << 1) | 1)) << 9) + (lane << 3));
                acc[t] = __builtin_amdgcn_mfma_f32_16x16x32_bf16(a_hi, wh, acc[t], 0, 0, 0);
                acc[t] = __builtin_amdgcn_mfma_f32_16x16x32_bf16(a_lo, wh, acc[t], 0, 0, 0);
                acc[t] = __builtin_amdgcn_mfma_f32_16x16x32_bf16(a_hi, wl, acc[t], 0, 0, 0);
            }
        }
        if (s < 7) {
            if (s + 1 < 4) a_cur = a_nxt; else { xv0 = xn0; xv1 = xn1; }
            __syncthreads();
        }
    }
    #undef STAGE

    if (HEAD) {
        float hs0 = 0.f, hs1 = 0.f, hs2 = 0.f, hs3 = 0.f;
        #pragma unroll
        for (int t = 0; t < 8; ++t) {
            int col = t * 16 + rit;
            float b = bias[col], w = hw[col];
            hs0 += fmaxf(acc[t][0] + b, 0.f) * w;
            hs1 += fmaxf(acc[t][1] + b, 0.f) * w;
            hs2 += fmaxf(acc[t][2] + b, 0.f) * w;
            hs3 += fmaxf(acc[t][3] + b, 0.f) * w;
        }
        #pragma unroll
        for (int msk = 1; msk < 16; msk <<= 1) {
            hs0 += __shfl_xor(hs0, msk, 64);
            hs1 += __shfl_xor(hs1, msk, 64);
            hs2 += __shfl_xor(hs2, msk, 64);
            hs3 += __shfl_xor(hs3, msk, 64);
        }
        if (rit == 0) {
            int r0 = m0 + kgrp * 4;
            float hbv = hb[0];
            if (r0     < n) hout[r0]     = hs0 + hbv;
            if (r0 + 1 < n) hout[r0 + 1] = hs1 + hbv;
            if (r0 + 2 < n) hout[r0 + 2] = hs2 + hbv;
            if (r0 + 3 < n) hout[r0 + 3] = hs3 + hbv;
        }
    } else {
        #pragma unroll
        for (int t = 0; t < 8; ++t) {
            int col = t * 16 + rit;
            float b = bias[col];
            #pragma unroll
            for (int j = 0; j < 4; ++j) {
                int rr = m0 + kgrp * 4 + j;
                float v = fmaxf(acc[t][j] + b, 0.f);
                if (rr < n) out[(size_t)rr * C + col] = v;
                float pv = __shfl_xor(v, 1, 64);
                if (!(rit & 1) && rr < n) {
                    u32 pkd = ((u32)f2bf(v)) | (((u32)f2bf(pv)) << 16);
                    outbf[(size_t)rr * 64 + (col >> 1)] = pkd;
                }
            }
        }
    }
}

// ---------------- launch ----------------

extern "C" void kernel_launch(void* const* d_in, const int* in_sizes, int n_in,
                              void* d_out, int out_size, void* d_ws, size_t ws_size,
                              hipStream_t stream) {
    const float* x     = (const float*)d_in[0];
    const int*   ei    = (const int*)d_in[1];
    const int*   src   = ei;
    const int*   dstp  = ei + NE;
    const float* sWl   = (const float*)d_in[2];
    const float* sB    = (const float*)d_in[3];
    const float* sWr   = (const float*)d_in[4];
    const float* rt1Wl = (const float*)d_in[5];
    const float* rt1B  = (const float*)d_in[6];
    const float* rt1Wr = (const float*)d_in[7];
    const float* rt2Wl = (const float*)d_in[8];
    const float* rt2B  = (const float*)d_in[9];
    const float* rt2Wr = (const float*)d_in[10];
    const float* rt3W  = (const float*)d_in[11];
    const float* rt3B  = (const float*)d_in[12];
    const float* mv1Wl = (const float*)d_in[13];
    const float* mv1B  = (const float*)d_in[14];
    const float* mv1Wr = (const float*)d_in[15];
    const float* mv2Wl = (const float*)d_in[16];
    const float* mv2B  = (const float*)d_in[17];
    const float* mv2Wr = (const float*)d_in[18];
    const float* mv3W  = (const float*)d_in[19];
    const float* mv3B  = (const float*)d_in[20];
    float* out = (float*)d_out;

    char* ws = (char*)d_ws;
    int* rowptr  = (int*)ws;                  // NN+1
    int* deg     = rowptr + (NN + 1);         // NN (consumed by fill)
    int* bsum    = deg + NN;                  // 64
    u16* esrc16  = (u16*)(bsum + 64);         // NE u16
    size_t off   = (((size_t)(NN + 1 + NN + 64) * 4 + (size_t)NE * 2) + 255) & ~(size_t)255;
    float* buf1  = (float*)(ws + off);        // fp32 layer outputs
    float* buf2  = buf1 + (size_t)NN * C;
    float* buf3  = buf2 + (size_t)NN * C;
    u32* aggbf   = (u32*)(buf3 + (size_t)NN * C);  // bf16 agg (NN*64 u32)
    u32* bf12    = aggbf + (size_t)NN * 64;        // bf16 copy: mv, then rt
    u32* bf3     = bf12 + (size_t)NN * 64;         // bf16 copy: md
    u32* xbf     = (u32*)buf3;                     // alias: dead before buf3 written
    u32* aggmd   = (u32*)buf1;                     // alias: buf1 dead after mv1-gemm
    u16* wpack   = (u16*)(bf3 + (size_t)NN * 64);
    u16* pk[5][2];
    for (int L = 0; L < 5; ++L) {
        pk[L][0] = wpack + (size_t)L * 65536;
        pk[L][1] = wpack + (size_t)L * 65536 + 32768;
    }

    const int TB = 256;
    const int NB = (NN + 1023) / 1024;
    const int GCH = ((NE + 4095) / 4096) * NR;  // 196 chunks x 8 ranges

    // weight packing + x conversion (independent of CSR build)
    k_packw<<<128, 256, 0, stream>>>(sWl,   sWr,   pk[0][0], pk[0][1]);
    k_packw<<<128, 256, 0, stream>>>(rt1Wl, rt1Wr, pk[1][0], pk[1][1]);
    k_packw<<<128, 256, 0, stream>>>(rt2Wl, rt2Wr, pk[2][0], pk[2][1]);
    k_packw<<<128, 256, 0, stream>>>(mv1Wl, mv1Wr, pk[3][0], pk[3][1]);
    k_packw<<<128, 256, 0, stream>>>(mv2Wl, mv2Wr, pk[4][0], pk[4][1]);
    k_cvt<<<(NN * 64 + 255) / 256, 256, 0, stream>>>(x, xbf, NN * 64);

    // CSR build (range-partitioned, XCD-affine heuristic)
    k_zero<<<(NN + TB - 1) / TB, TB, 0, stream>>>(deg, NN);
    k_hist_x<<<GCH, 256, 0, stream>>>(dstp, deg, NE);
    k_scan_blk<<<NB, 1024, 0, stream>>>(deg, rowptr, bsum, NN);
    k_scan_sums<<<1, 64, 0, stream>>>(bsum, NB);
    k_scan_add<<<NB, 1024, 0, stream>>>(rowptr, bsum, NN);
    k_fill_x<<<GCH, 256, 0, stream>>>(src, dstp, rowptr, deg, esrc16, NE);

    dim3 gSeg((NN + 3) / 4), bSeg(256);
    dim3 gGem((NN + 63) / 64), bGem(256);

    // shared layer: mv = relu(sage(x))
    k_segmax_bf<<<gSeg, bSeg, 0, stream>>>(xbf, rowptr, esrc16, aggbf, NN);
    k_gemm_s<0><<<gGem, bGem, 0, stream>>>((const u16*)aggbf, x, pk[0][0], pk[0][1],
                                           sB, buf1, bf12, nullptr, nullptr, nullptr, NN);
    // agg(mv) shared by rt1 and mv1
    k_segmax_bf<<<gSeg, bSeg, 0, stream>>>(bf12, rowptr, esrc16, aggbf, NN);
    k_gemm_s<0><<<gGem, bGem, 0, stream>>>((const u16*)aggbf, buf1, pk[1][0], pk[1][1],
                                           rt1B, buf2, bf12, nullptr, nullptr, nullptr, NN); // rt
    k_gemm_s<0><<<gGem, bGem, 0, stream>>>((const u16*)aggbf, buf1, pk[3][0], pk[3][1],
                                           mv1B, buf3, bf3, nullptr, nullptr, nullptr, NN);  // md
    // fused dual aggregation: agg(rt) -> aggbf, agg(md) -> aggmd (buf1 alias)
    k_segmax_bf2<<<gSeg, bSeg, 0, stream>>>(bf12, bf3, rowptr, esrc16, aggbf, aggmd, NN);
    // rt branch layer 2 + fused rt3 head
    k_gemm_s<1><<<gGem, bGem, 0, stream>>>((const u16*)aggbf, buf2, pk[2][0], pk[2][1],
                                           rt2B, nullptr, nullptr, rt3W, rt3B, out, NN);
    // md branch layer 2 + fused mv3 head
    k_gemm_s<1><<<gGem, bGem, 0, stream>>>((const u16*)aggmd, buf3, pk[4][0], pk[4][1],
                                           mv2B, nullptr, nullptr, mv3W, mv3B, out + NN, NN);
}

// Round 8
// 327.856 us; speedup vs baseline: 2.2037x; 1.0165x over previous
//
#include <hip/hip_runtime.h>
#include <hip/hip_bf16.h>
#include <math.h>

#define NN 50000
#define NE 800000
#define C  128
#define NR 8            // dst ranges (XCD-affine via blockIdx%8 heuristic)
#define RNG (NN / NR)
typedef unsigned int u32;
typedef unsigned short u16;

using f32x4  = __attribute__((ext_vector_type(4))) float;
using short8 = __attribute__((ext_vector_type(8))) short;

__device__ __forceinline__ u16 f2bf(float f) {
    u32 u = __float_as_uint(f);
    u32 r = u + 0x7FFFu + ((u >> 16) & 1u);
    return (u16)(r >> 16);
}
__device__ __forceinline__ float bf2f(u16 h) {
    return __uint_as_float(((u32)h) << 16);
}

__device__ __forceinline__ void gload_lds16(const u16* g, u16* l) {
    __builtin_amdgcn_global_load_lds(
        (const __attribute__((address_space(1))) u32*)g,
        (__attribute__((address_space(3))) u32*)l,
        16, 0, 0);
}

// ---------------- CSR build ----------------

__global__ void k_zero(int* __restrict__ p, int n) {
    int i = blockIdx.x * blockDim.x + threadIdx.x;
    if (i < n) p[i] = 0;
}

__global__ __launch_bounds__(256) void k_hist_x(const int* __restrict__ dst, int* __restrict__ deg, int nE) {
    int r    = blockIdx.x & (NR - 1);
    int base = (blockIdx.x >> 3) * 4096;
    int lo   = r * RNG, hi = lo + RNG;
    #pragma unroll
    for (int it = 0; it < 16; ++it) {
        int e = base + it * 256 + threadIdx.x;
        if (e < nE) {
            int d = dst[e];
            if (d >= lo && d < hi) atomicAdd(&deg[d], 1);
        }
    }
}

__global__ __launch_bounds__(1024) void k_scan_blk(const int* __restrict__ deg, int* __restrict__ rowptr,
                                                   int* __restrict__ bsum, int n) {
    __shared__ int wsum[16];
    int tid = threadIdx.x, lane = tid & 63, wid = tid >> 6;
    int i = blockIdx.x * 1024 + tid;
    int v = (i < n) ? deg[i] : 0;
    int incl = v;
    #pragma unroll
    for (int d = 1; d < 64; d <<= 1) {
        int t = __shfl_up(incl, d, 64);
        if (lane >= d) incl += t;
    }
    if (lane == 63) wsum[wid] = incl;
    __syncthreads();
    int wo = 0;
    #pragma unroll
    for (int w = 0; w < 16; ++w) wo += (w < wid) ? wsum[w] : 0;
    if (i < n) rowptr[i + 1] = wo + incl;
    if (tid == 1023) bsum[blockIdx.x] = wo + incl;
}

__global__ void k_scan_sums(int* __restrict__ bsum, int nb) {
    int lane = threadIdx.x;
    int v = (lane < nb) ? bsum[lane] : 0;
    int incl = v;
    #pragma unroll
    for (int d = 1; d < 64; d <<= 1) {
        int t = __shfl_up(incl, d, 64);
        if (lane >= d) incl += t;
    }
    if (lane < nb) bsum[lane] = incl - v;  // exclusive
}

__global__ __launch_bounds__(1024) void k_scan_add(int* __restrict__ rowptr, const int* __restrict__ bsum, int n) {
    int i = blockIdx.x * 1024 + threadIdx.x;
    if (i == 0) rowptr[0] = 0;
    if (i < n) rowptr[i + 1] += bsum[blockIdx.x];
}

__global__ __launch_bounds__(256) void k_fill_x(const int* __restrict__ src, const int* __restrict__ dst,
                                                const int* __restrict__ rowptr, int* __restrict__ deg,
                                                u16* __restrict__ esrc, int nE) {
    int r    = blockIdx.x & (NR - 1);
    int base = (blockIdx.x >> 3) * 4096;
    int lo   = r * RNG, hi = lo + RNG;
    #pragma unroll
    for (int it = 0; it < 16; ++it) {
        int e = base + it * 256 + threadIdx.x;
        if (e < nE) {
            int d = dst[e];
            if (d >= lo && d < hi) {
                int old = atomicSub(&deg[d], 1);
                esrc[rowptr[d + 1] - old] = (u16)src[e];
            }
        }
    }
}

// ---------------- fp32 -> bf16 hi/lo plane split (for x) ----------------
__global__ void k_cvt2(const float* __restrict__ in, u32* __restrict__ oh, u32* __restrict__ ol, int n64) {
    int i = blockIdx.x * 256 + threadIdx.x;
    if (i < n64) {
        float2 v = *(const float2*)(in + (size_t)i * 2);
        u16 h0 = f2bf(v.x), h1 = f2bf(v.y);
        oh[i] = ((u32)h0) | (((u32)h1) << 16);
        u16 l0 = f2bf(v.x - bf2f(h0)), l1 = f2bf(v.y - bf2f(h1));
        ol[i] = ((u32)l0) | (((u32)l1) << 16);
    }
}

// ---------------- segment max over packed bf16 ----------------
#define UPK(w_, lo_, hi_) { lo_ = fmaxf(lo_, __uint_as_float((w_) << 16)); \
                            hi_ = fmaxf(hi_, __uint_as_float((w_) & 0xFFFF0000u)); }

__global__ __launch_bounds__(256) void k_segmax_bf(const u32* __restrict__ h2, const int* __restrict__ rowptr,
                                                   const u16* __restrict__ esrc, u32* __restrict__ agg2, int n) {
    int node = blockIdx.x * 4 + (threadIdx.x >> 6);
    int lane = threadIdx.x & 63;
    if (node >= n) return;
    int beg = rowptr[node], end = rowptr[node + 1];
    float mlo = -INFINITY, mhi = -INFINITY;
    int i = beg;
    for (; i + 7 < end; i += 8) {
        u32 w0 = h2[((size_t)esrc[i]     << 6) + lane];
        u32 w1 = h2[((size_t)esrc[i + 1] << 6) + lane];
        u32 w2 = h2[((size_t)esrc[i + 2] << 6) + lane];
        u32 w3 = h2[((size_t)esrc[i + 3] << 6) + lane];
        u32 w4 = h2[((size_t)esrc[i + 4] << 6) + lane];
        u32 w5 = h2[((size_t)esrc[i + 5] << 6) + lane];
        u32 w6 = h2[((size_t)esrc[i + 6] << 6) + lane];
        u32 w7 = h2[((size_t)esrc[i + 7] << 6) + lane];
        UPK(w0, mlo, mhi) UPK(w1, mlo, mhi) UPK(w2, mlo, mhi) UPK(w3, mlo, mhi)
        UPK(w4, mlo, mhi) UPK(w5, mlo, mhi) UPK(w6, mlo, mhi) UPK(w7, mlo, mhi)
    }
    for (; i < end; ++i) { u32 w = h2[((size_t)esrc[i] << 6) + lane]; UPK(w, mlo, mhi) }
    u32 r = 0u;
    if (end > beg)
        r = (__float_as_uint(mlo) >> 16) | (__float_as_uint(mhi) & 0xFFFF0000u);
    __builtin_nontemporal_store(r, &agg2[(size_t)node * 64 + lane]);
}

// dual: two feature arrays over the same edges, 16 gathers in flight
__global__ __launch_bounds__(256) void k_segmax_bf2(const u32* __restrict__ hA, const u32* __restrict__ hB,
                                                    const int* __restrict__ rowptr, const u16* __restrict__ esrc,
                                                    u32* __restrict__ aggA, u32* __restrict__ aggB, int n) {
    int node = blockIdx.x * 4 + (threadIdx.x >> 6);
    int lane = threadIdx.x & 63;
    if (node >= n) return;
    int beg = rowptr[node], end = rowptr[node + 1];
    float alo = -INFINITY, ahi = -INFINITY, blo = -INFINITY, bhi = -INFINITY;
    int i = beg;
    for (; i + 7 < end; i += 8) {
        size_t b0 = ((size_t)esrc[i]     << 6) + lane;
        size_t b1 = ((size_t)esrc[i + 1] << 6) + lane;
        size_t b2 = ((size_t)esrc[i + 2] << 6) + lane;
        size_t b3 = ((size_t)esrc[i + 3] << 6) + lane;
        size_t b4 = ((size_t)esrc[i + 4] << 6) + lane;
        size_t b5 = ((size_t)esrc[i + 5] << 6) + lane;
        size_t b6 = ((size_t)esrc[i + 6] << 6) + lane;
        size_t b7 = ((size_t)esrc[i + 7] << 6) + lane;
        u32 a0 = hA[b0], a1 = hA[b1], a2 = hA[b2], a3 = hA[b3];
        u32 a4 = hA[b4], a5 = hA[b5], a6 = hA[b6], a7 = hA[b7];
        u32 q0 = hB[b0], q1 = hB[b1], q2 = hB[b2], q3 = hB[b3];
        u32 q4 = hB[b4], q5 = hB[b5], q6 = hB[b6], q7 = hB[b7];
        UPK(a0, alo, ahi) UPK(a1, alo, ahi) UPK(a2, alo, ahi) UPK(a3, alo, ahi)
        UPK(a4, alo, ahi) UPK(a5, alo, ahi) UPK(a6, alo, ahi) UPK(a7, alo, ahi)
        UPK(q0, blo, bhi) UPK(q1, blo, bhi) UPK(q2, blo, bhi) UPK(q3, blo, bhi)
        UPK(q4, blo, bhi) UPK(q5, blo, bhi) UPK(q6, blo, bhi) UPK(q7, blo, bhi)
    }
    for (; i < end; ++i) {
        size_t b = ((size_t)esrc[i] << 6) + lane;
        u32 a = hA[b], q = hB[b];
        UPK(a, alo, ahi) UPK(q, blo, bhi)
    }
    u32 ra = 0u, rb = 0u;
    if (end > beg) {
        ra = (__float_as_uint(alo) >> 16) | (__float_as_uint(ahi) & 0xFFFF0000u);
        rb = (__float_as_uint(blo) >> 16) | (__float_as_uint(bhi) & 0xFFFF0000u);
    }
    __builtin_nontemporal_store(ra, &aggA[(size_t)node * 64 + lane]);
    __builtin_nontemporal_store(rb, &aggB[(size_t)node * 64 + lane]);
}

// ---------------- weight pack: fragment-order bf16 hi/lo ----------------
__global__ void k_packw(const float* __restrict__ Wl, const float* __restrict__ Wr,
                        u16* __restrict__ Wh, u16* __restrict__ Wlo) {
    int idx = blockIdx.x * 256 + threadIdx.x;
    if (idx >= 128 * 256) return;
    int j = idx & 7, l = (idx >> 3) & 63, s = (idx >> 9) & 7, t = idx >> 12;
    int nrow = t * 16 + (l & 15);
    int k    = s * 32 + (l >> 4) * 8 + j;
    float v  = (k < 128) ? Wl[nrow * 128 + k] : Wr[nrow * 128 + (k - 128)];
    u16 h = f2bf(v);
    Wh[idx]  = h;
    Wlo[idx] = f2bf(v - bf2f(h));
}

// ---------------- plane-input MFMA SAGE gemm (BM=128, M=32/wave) ----------------
// A (agg) exact bf16 hi-plane; X as bf16 hi/lo planes (producer-split).
// out = hi/lo planes of relu(A@Wl^T + X@Wr^T + b). HEAD: fused 128->1 dot.
template<int HEAD>
__global__ __launch_bounds__(256) void k_gemm_p(
        const u16* __restrict__ Ahi, const u16* __restrict__ Xh, const u16* __restrict__ Xl,
        const u16* __restrict__ Wh, const u16* __restrict__ Wlo,
        const float* __restrict__ bias, u32* __restrict__ outh, u32* __restrict__ outl,
        const float* __restrict__ hw, const float* __restrict__ hb,
        float* __restrict__ hout, int n) {
    __shared__ __align__(16) u16 smw[2][8192];
    int tid  = threadIdx.x;
    int wave = tid >> 6, lane = tid & 63;
    int rit  = lane & 15, kgrp = lane >> 4;
    int m0   = blockIdx.x * 128 + wave * 32;
    int ar0  = m0 + rit;      if (ar0 > n - 1) ar0 = n - 1;
    int ar1  = m0 + 16 + rit; if (ar1 > n - 1) ar1 = n - 1;

    f32x4 acc0[8], acc1[8];
    #pragma unroll
    for (int t = 0; t < 8; ++t) {
        acc0[t] = (f32x4){0.f, 0.f, 0.f, 0.f};
        acc1[t] = (f32x4){0.f, 0.f, 0.f, 0.f};
    }

    #define STAGE(s_, b_) do {                                                   \
        _Pragma("unroll")                                                        \
        for (int q = 0; q < 4; ++q) {                                            \
            int kk = wave * 4 + q;                                               \
            int tt = kk >> 1;                                                    \
            const u16* g = ((kk & 1) ? Wlo : Wh)                                 \
                           + (((tt << 3) + (s_)) << 9) + (lane << 3);            \
            gload_lds16(g, &smw[b_][kk << 9]);                                   \
        }                                                                        \
    } while (0)

    short8 c0, c1, c2, c3, p0, p1, p2, p3;
    STAGE(0, 0);
    c0 = *(const short8*)(Ahi + (size_t)ar0 * C + kgrp * 8);
    c1 = *(const short8*)(Ahi + (size_t)ar1 * C + kgrp * 8);
    __syncthreads();

    #pragma unroll
    for (int s = 0; s < 8; ++s) {
        if (s < 7) {
            STAGE(s + 1, (s + 1) & 1);
            if (s + 1 < 4) {
                p0 = *(const short8*)(Ahi + (size_t)ar0 * C + (s + 1) * 32 + kgrp * 8);
                p1 = *(const short8*)(Ahi + (size_t)ar1 * C + (s + 1) * 32 + kgrp * 8);
            } else {
                size_t o0 = (size_t)ar0 * C + (s + 1 - 4) * 32 + kgrp * 8;
                size_t o1 = (size_t)ar1 * C + (s + 1 - 4) * 32 + kgrp * 8;
                p0 = *(const short8*)(Xh + o0);
                p1 = *(const short8*)(Xl + o0);
                p2 = *(const short8*)(Xh + o1);
                p3 = *(const short8*)(Xl + o1);
            }
        }
        const u16* base = smw[s & 1];
        if (s < 4) {
            #pragma unroll
            for (int t = 0; t < 8; ++t) {
                short8 wh = *(const short8*)(base + ((t << 1) << 9)         + (lane << 3));
                short8 wl = *(const short8*)(base + ((((t << 1) | 1)) << 9) + (lane << 3));
                acc0[t] = __builtin_amdgcn_mfma_f32_16x16x32_bf16(c0, wh, acc0[t], 0, 0, 0);
                acc0[t] = __builtin_amdgcn_mfma_f32_16x16x32_bf16(c0, wl, acc0[t], 0, 0, 0);
                acc1[t] = __builtin_amdgcn_mfma_f32_16x16x32_bf16(c1, wh, acc1[t], 0, 0, 0);
                acc1[t] = __builtin_amdgcn_mfma_f32_16x16x32_bf16(c1, wl, acc1[t], 0, 0, 0);
            }
        } else {
            // c0=XH0, c1=XL0, c2=XH1, c3=XL1
            #pragma unroll
            for (int t = 0; t < 8; ++t) {
                short8 wh = *(const short8*)(base + ((t << 1) << 9)         + (lane << 3));
                short8 wl = *(const short8*)(base + ((((t << 1) | 1)) << 9) + (lane << 3));
                acc0[t] = __builtin_amdgcn_mfma_f32_16x16x32_bf16(c0, wh, acc0[t], 0, 0, 0);
                acc0[t] = __builtin_amdgcn_mfma_f32_16x16x32_bf16(c1, wh, acc0[t], 0, 0, 0);
                acc0[t] = __builtin_amdgcn_mfma_f32_16x16x32_bf16(c0, wl, acc0[t], 0, 0, 0);
                acc1[t] = __builtin_amdgcn_mfma_f32_16x16x32_bf16(c2, wh, acc1[t], 0, 0, 0);
                acc1[t] = __builtin_amdgcn_mfma_f32_16x16x32_bf16(c3, wh, acc1[t], 0, 0, 0);
                acc1[t] = __builtin_amdgcn_mfma_f32_16x16x32_bf16(c2, wl, acc1[t], 0, 0, 0);
            }
        }
        if (s < 7) {
            c0 = p0; c1 = p1; c2 = p2; c3 = p3;
            __syncthreads();
        }
    }
    #undef STAGE

    if (HEAD) {
        float hsA[4] = {0.f, 0.f, 0.f, 0.f}, hsB[4] = {0.f, 0.f, 0.f, 0.f};
        #pragma unroll
        for (int t = 0; t < 8; ++t) {
            int col = t * 16 + rit;
            float b = bias[col], w = hw[col];
            #pragma unroll
            for (int j = 0; j < 4; ++j) {
                hsA[j] += fmaxf(acc0[t][j] + b, 0.f) * w;
                hsB[j] += fmaxf(acc1[t][j] + b, 0.f) * w;
            }
        }
        #pragma unroll
        for (int msk = 1; msk < 16; msk <<= 1) {
            #pragma unroll
            for (int j = 0; j < 4; ++j) {
                hsA[j] += __shfl_xor(hsA[j], msk, 64);
                hsB[j] += __shfl_xor(hsB[j], msk, 64);
            }
        }
        if (rit == 0) {
            float hbv = hb[0];
            #pragma unroll
            for (int j = 0; j < 4; ++j) {
                int rA = m0 + kgrp * 4 + j;
                int rB = rA + 16;
                if (rA < n) hout[rA] = hsA[j] + hbv;
                if (rB < n) hout[rB] = hsB[j] + hbv;
            }
        }
    } else {
        #pragma unroll
        for (int g = 0; g < 2; ++g) {
            int rbase = m0 + g * 16 + kgrp * 4;
            #pragma unroll
            for (int t = 0; t < 8; ++t) {
                int col = t * 16 + rit;
                float b = bias[col];
                #pragma unroll
                for (int j = 0; j < 4; ++j) {
                    int rr = rbase + j;
                    float v = fmaxf((g ? acc1[t][j] : acc0[t][j]) + b, 0.f);
                    float pv = __shfl_xor(v, 1, 64);
                    if (!(rit & 1) && rr < n) {
                        u16 h  = f2bf(v),              ph  = f2bf(pv);
                        u16 lo = f2bf(v - bf2f(h)),    plo = f2bf(pv - bf2f(ph));
                        outh[(size_t)rr * 64 + (col >> 1)] = ((u32)h)  | (((u32)ph)  << 16);
                        outl[(size_t)rr * 64 + (col >> 1)] = ((u32)lo) | (((u32)plo) << 16);
                    }
                }
            }
        }
    }
}

// ---------------- launch ----------------

extern "C" void kernel_launch(void* const* d_in, const int* in_sizes, int n_in,
                              void* d_out, int out_size, void* d_ws, size_t ws_size,
                              hipStream_t stream) {
    const float* x     = (const float*)d_in[0];
    const int*   ei    = (const int*)d_in[1];
    const int*   src   = ei;
    const int*   dstp  = ei + NE;
    const float* sWl   = (const float*)d_in[2];
    const float* sB    = (const float*)d_in[3];
    const float* sWr   = (const float*)d_in[4];
    const float* rt1Wl = (const float*)d_in[5];
    const float* rt1B  = (const float*)d_in[6];
    const float* rt1Wr = (const float*)d_in[7];
    const float* rt2Wl = (const float*)d_in[8];
    const float* rt2B  = (const float*)d_in[9];
    const float* rt2Wr = (const float*)d_in[10];
    const float* rt3W  = (const float*)d_in[11];
    const float* rt3B  = (const float*)d_in[12];
    const float* mv1Wl = (const float*)d_in[13];
    const float* mv1B  = (const float*)d_in[14];
    const float* mv1Wr = (const float*)d_in[15];
    const float* mv2Wl = (const float*)d_in[16];
    const float* mv2B  = (const float*)d_in[17];
    const float* mv2Wr = (const float*)d_in[18];
    const float* mv3W  = (const float*)d_in[19];
    const float* mv3B  = (const float*)d_in[20];
    float* out = (float*)d_out;

    char* ws = (char*)d_ws;
    int* rowptr  = (int*)ws;                  // NN+1
    int* deg     = rowptr + (NN + 1);         // NN
    int* bsum    = deg + NN;                  // 64
    u16* esrc16  = (u16*)(bsum + 64);         // NE u16
    size_t off   = (((size_t)(NN + 1 + NN + 64) * 4 + (size_t)NE * 2) + 255) & ~(size_t)255;
    // 7 bf16 planes, each NN*64 u32 = 12.8 MB
    u32* P[7];
    for (int i = 0; i < 7; ++i) P[i] = (u32*)(ws + off) + (size_t)i * NN * 64;
    u16* wpack = (u16*)(P[6] + (size_t)NN * 64);
    u16* pk[5][2];
    for (int L = 0; L < 5; ++L) {
        pk[L][0] = wpack + (size_t)L * 65536;
        pk[L][1] = wpack + (size_t)L * 65536 + 32768;
    }

    const int TB = 256;
    const int NB = (NN + 1023) / 1024;
    const int GCH = ((NE + 4095) / 4096) * NR;

    // weight packing + x plane split (independent of CSR build)
    k_packw<<<128, 256, 0, stream>>>(sWl,   sWr,   pk[0][0], pk[0][1]);
    k_packw<<<128, 256, 0, stream>>>(rt1Wl, rt1Wr, pk[1][0], pk[1][1]);
    k_packw<<<128, 256, 0, stream>>>(rt2Wl, rt2Wr, pk[2][0], pk[2][1]);
    k_packw<<<128, 256, 0, stream>>>(mv1Wl, mv1Wr, pk[3][0], pk[3][1]);
    k_packw<<<128, 256, 0, stream>>>(mv2Wl, mv2Wr, pk[4][0], pk[4][1]);
    k_cvt2<<<(NN * 64 + 255) / 256, 256, 0, stream>>>(x, P[0], P[1], NN * 64);  // xh, xl

    // CSR build (range-partitioned, XCD-affine heuristic)
    k_zero<<<(NN + TB - 1) / TB, TB, 0, stream>>>(deg, NN);
    k_hist_x<<<GCH, 256, 0, stream>>>(dstp, deg, NE);
    k_scan_blk<<<NB, 1024, 0, stream>>>(deg, rowptr, bsum, NN);
    k_scan_sums<<<1, 64, 0, stream>>>(bsum, NB);
    k_scan_add<<<NB, 1024, 0, stream>>>(rowptr, bsum, NN);
    k_fill_x<<<GCH, 256, 0, stream>>>(src, dstp, rowptr, deg, esrc16, NE);

    dim3 gSeg((NN + 3) / 4), bSeg(256);
    dim3 gGem((NN + 127) / 128), bGem(256);

    // shared layer: mv = relu(sage(x));  agg(x)->P2, mv planes -> P3,P4
    k_segmax_bf<<<gSeg, bSeg, 0, stream>>>(P[0], rowptr, esrc16, P[2], NN);
    k_gemm_p<0><<<gGem, bGem, 0, stream>>>((const u16*)P[2], (const u16*)P[0], (const u16*)P[1],
                                           pk[0][0], pk[0][1], sB, P[3], P[4],
                                           nullptr, nullptr, nullptr, NN);
    // agg(mv) -> P5, shared by rt1 and mv1
    k_segmax_bf<<<gSeg, bSeg, 0, stream>>>(P[3], rowptr, esrc16, P[5], NN);
    k_gemm_p<0><<<gGem, bGem, 0, stream>>>((const u16*)P[5], (const u16*)P[3], (const u16*)P[4],
                                           pk[1][0], pk[1][1], rt1B, P[0], P[1],
                                           nullptr, nullptr, nullptr, NN);   // rt -> P0,P1
    k_gemm_p<0><<<gGem, bGem, 0, stream>>>((const u16*)P[5], (const u16*)P[3], (const u16*)P[4],
                                           pk[3][0], pk[3][1], mv1B, P[2], P[6],
                                           nullptr, nullptr, nullptr, NN);   // md -> P2,P6
    // fused dual aggregation: agg(rt) -> P3, agg(md) -> P4
    k_segmax_bf2<<<gSeg, bSeg, 0, stream>>>(P[0], P[2], rowptr, esrc16, P[3], P[4], NN);
    // rt branch layer 2 + fused rt3 head
    k_gemm_p<1><<<gGem, bGem, 0, stream>>>((const u16*)P[3], (const u16*)P[0], (const u16*)P[1],
                                           pk[2][0], pk[2][1], rt2B, nullptr, nullptr,
                                           rt3W, rt3B, out, NN);
    // md branch layer 2 + fused mv3 head
    k_gemm_p<1><<<gGem, bGem, 0, stream>>>((const u16*)P[4], (const u16*)P[2], (const u16*)P[6],
                                           pk[4][0], pk[4][1], mv2B, nullptr, nullptr,
                                           mv3W, mv3B, out + NN, NN);
}

// Round 9
// 325.434 us; speedup vs baseline: 2.2201x; 1.0074x over previous
//
#include <hip/hip_runtime.h>
#include <hip/hip_bf16.h>
#include <math.h>

#define NN 50000
#define NE 800000
#define C  128
#define NR 8            // dst ranges (XCD-affine via blockIdx%8 heuristic)
#define RNG (NN / NR)
typedef unsigned int u32;
typedef unsigned short u16;

using f32x4  = __attribute__((ext_vector_type(4))) float;
using short8 = __attribute__((ext_vector_type(8))) short;

__device__ __forceinline__ u16 f2bf(float f) {
    u32 u = __float_as_uint(f);
    u32 r = u + 0x7FFFu + ((u >> 16) & 1u);
    return (u16)(r >> 16);
}
__device__ __forceinline__ float bf2f(u16 h) {
    return __uint_as_float(((u32)h) << 16);
}

__device__ __forceinline__ void gload_lds16(const u16* g, u16* l) {
    __builtin_amdgcn_global_load_lds(
        (const __attribute__((address_space(1))) u32*)g,
        (__attribute__((address_space(3))) u32*)l,
        16, 0, 0);
}

// ---------------- CSR build ----------------

__global__ void k_zero(int* __restrict__ p, int n) {
    int i = blockIdx.x * blockDim.x + threadIdx.x;
    if (i < n) p[i] = 0;
}

__global__ __launch_bounds__(256) void k_hist_x(const int* __restrict__ dst, int* __restrict__ deg, int nE) {
    int r    = blockIdx.x & (NR - 1);
    int base = (blockIdx.x >> 3) * 4096;
    int lo   = r * RNG, hi = lo + RNG;
    #pragma unroll
    for (int it = 0; it < 16; ++it) {
        int e = base + it * 256 + threadIdx.x;
        if (e < nE) {
            int d = dst[e];
            if (d >= lo && d < hi) atomicAdd(&deg[d], 1);
        }
    }
}

__global__ __launch_bounds__(1024) void k_scan_blk(const int* __restrict__ deg, int* __restrict__ rowptr,
                                                   int* __restrict__ bsum, int n) {
    __shared__ int wsum[16];
    int tid = threadIdx.x, lane = tid & 63, wid = tid >> 6;
    int i = blockIdx.x * 1024 + tid;
    int v = (i < n) ? deg[i] : 0;
    int incl = v;
    #pragma unroll
    for (int d = 1; d < 64; d <<= 1) {
        int t = __shfl_up(incl, d, 64);
        if (lane >= d) incl += t;
    }
    if (lane == 63) wsum[wid] = incl;
    __syncthreads();
    int wo = 0;
    #pragma unroll
    for (int w = 0; w < 16; ++w) wo += (w < wid) ? wsum[w] : 0;
    if (i < n) rowptr[i + 1] = wo + incl;
    if (tid == 1023) bsum[blockIdx.x] = wo + incl;
}

__global__ void k_scan_sums(int* __restrict__ bsum, int nb) {
    int lane = threadIdx.x;
    int v = (lane < nb) ? bsum[lane] : 0;
    int incl = v;
    #pragma unroll
    for (int d = 1; d < 64; d <<= 1) {
        int t = __shfl_up(incl, d, 64);
        if (lane >= d) incl += t;
    }
    if (lane < nb) bsum[lane] = incl - v;  // exclusive
}

__global__ __launch_bounds__(1024) void k_scan_add(int* __restrict__ rowptr, const int* __restrict__ bsum, int n) {
    int i = blockIdx.x * 1024 + threadIdx.x;
    if (i == 0) rowptr[0] = 0;
    if (i < n) rowptr[i + 1] += bsum[blockIdx.x];
}

__global__ __launch_bounds__(256) void k_fill_x(const int* __restrict__ src, const int* __restrict__ dst,
                                                const int* __restrict__ rowptr, int* __restrict__ deg,
                                                u16* __restrict__ esrc, int nE) {
    int r    = blockIdx.x & (NR - 1);
    int base = (blockIdx.x >> 3) * 4096;
    int lo   = r * RNG, hi = lo + RNG;
    #pragma unroll
    for (int it = 0; it < 16; ++it) {
        int e = base + it * 256 + threadIdx.x;
        if (e < nE) {
            int d = dst[e];
            if (d >= lo && d < hi) {
                int old = atomicSub(&deg[d], 1);
                esrc[rowptr[d + 1] - old] = (u16)src[e];
            }
        }
    }
}

// ---------------- fp32 -> bf16 hi/lo plane split (for x) ----------------
__global__ void k_cvt2(const float* __restrict__ in, u32* __restrict__ oh, u32* __restrict__ ol, int n64) {
    int i = blockIdx.x * 256 + threadIdx.x;
    if (i < n64) {
        float2 v = *(const float2*)(in + (size_t)i * 2);
        u16 h0 = f2bf(v.x), h1 = f2bf(v.y);
        oh[i] = ((u32)h0) | (((u32)h1) << 16);
        u16 l0 = f2bf(v.x - bf2f(h0)), l1 = f2bf(v.y - bf2f(h1));
        ol[i] = ((u32)l0) | (((u32)l1) << 16);
    }
}

// ---------------- segment max over packed bf16 ----------------
#define UPK(w_, lo_, hi_) { lo_ = fmaxf(lo_, __uint_as_float((w_) << 16)); \
                            hi_ = fmaxf(hi_, __uint_as_float((w_) & 0xFFFF0000u)); }

__global__ __launch_bounds__(256) void k_segmax_bf(const u32* __restrict__ h2, const int* __restrict__ rowptr,
                                                   const u16* __restrict__ esrc, u32* __restrict__ agg2, int n) {
    int node = blockIdx.x * 4 + (threadIdx.x >> 6);
    int lane = threadIdx.x & 63;
    if (node >= n) return;
    int beg = rowptr[node], end = rowptr[node + 1];
    float mlo = -INFINITY, mhi = -INFINITY;
    int i = beg;
    for (; i + 7 < end; i += 8) {
        u32 w0 = h2[((size_t)esrc[i]     << 6) + lane];
        u32 w1 = h2[((size_t)esrc[i + 1] << 6) + lane];
        u32 w2 = h2[((size_t)esrc[i + 2] << 6) + lane];
        u32 w3 = h2[((size_t)esrc[i + 3] << 6) + lane];
        u32 w4 = h2[((size_t)esrc[i + 4] << 6) + lane];
        u32 w5 = h2[((size_t)esrc[i + 5] << 6) + lane];
        u32 w6 = h2[((size_t)esrc[i + 6] << 6) + lane];
        u32 w7 = h2[((size_t)esrc[i + 7] << 6) + lane];
        UPK(w0, mlo, mhi) UPK(w1, mlo, mhi) UPK(w2, mlo, mhi) UPK(w3, mlo, mhi)
        UPK(w4, mlo, mhi) UPK(w5, mlo, mhi) UPK(w6, mlo, mhi) UPK(w7, mlo, mhi)
    }
    for (; i < end; ++i) { u32 w = h2[((size_t)esrc[i] << 6) + lane]; UPK(w, mlo, mhi) }
    u32 r = 0u;
    if (end > beg)
        r = (__float_as_uint(mlo) >> 16) | (__float_as_uint(mhi) & 0xFFFF0000u);
    __builtin_nontemporal_store(r, &agg2[(size_t)node * 64 + lane]);
}

// dual: two feature arrays over the same edges, 16 gathers in flight
__global__ __launch_bounds__(256) void k_segmax_bf2(const u32* __restrict__ hA, const u32* __restrict__ hB,
                                                    const int* __restrict__ rowptr, const u16* __restrict__ esrc,
                                                    u32* __restrict__ aggA, u32* __restrict__ aggB, int n) {
    int node = blockIdx.x * 4 + (threadIdx.x >> 6);
    int lane = threadIdx.x & 63;
    if (node >= n) return;
    int beg = rowptr[node], end = rowptr[node + 1];
    float alo = -INFINITY, ahi = -INFINITY, blo = -INFINITY, bhi = -INFINITY;
    int i = beg;
    for (; i + 7 < end; i += 8) {
        size_t b0 = ((size_t)esrc[i]     << 6) + lane;
        size_t b1 = ((size_t)esrc[i + 1] << 6) + lane;
        size_t b2 = ((size_t)esrc[i + 2] << 6) + lane;
        size_t b3 = ((size_t)esrc[i + 3] << 6) + lane;
        size_t b4 = ((size_t)esrc[i + 4] << 6) + lane;
        size_t b5 = ((size_t)esrc[i + 5] << 6) + lane;
        size_t b6 = ((size_t)esrc[i + 6] << 6) + lane;
        size_t b7 = ((size_t)esrc[i + 7] << 6) + lane;
        u32 a0 = hA[b0], a1 = hA[b1], a2 = hA[b2], a3 = hA[b3];
        u32 a4 = hA[b4], a5 = hA[b5], a6 = hA[b6], a7 = hA[b7];
        u32 q0 = hB[b0], q1 = hB[b1], q2 = hB[b2], q3 = hB[b3];
        u32 q4 = hB[b4], q5 = hB[b5], q6 = hB[b6], q7 = hB[b7];
        UPK(a0, alo, ahi) UPK(a1, alo, ahi) UPK(a2, alo, ahi) UPK(a3, alo, ahi)
        UPK(a4, alo, ahi) UPK(a5, alo, ahi) UPK(a6, alo, ahi) UPK(a7, alo, ahi)
        UPK(q0, blo, bhi) UPK(q1, blo, bhi) UPK(q2, blo, bhi) UPK(q3, blo, bhi)
        UPK(q4, blo, bhi) UPK(q5, blo, bhi) UPK(q6, blo, bhi) UPK(q7, blo, bhi)
    }
    for (; i < end; ++i) {
        size_t b = ((size_t)esrc[i] << 6) + lane;
        u32 a = hA[b], q = hB[b];
        UPK(a, alo, ahi) UPK(q, blo, bhi)
    }
    u32 ra = 0u, rb = 0u;
    if (end > beg) {
        ra = (__float_as_uint(alo) >> 16) | (__float_as_uint(ahi) & 0xFFFF0000u);
        rb = (__float_as_uint(blo) >> 16) | (__float_as_uint(bhi) & 0xFFFF0000u);
    }
    __builtin_nontemporal_store(ra, &aggA[(size_t)node * 64 + lane]);
    __builtin_nontemporal_store(rb, &aggB[(size_t)node * 64 + lane]);
}

// ---------------- weight pack: all 5 layers in one dispatch ----------------
struct PackArgs {
    const float* Wl[5]; const float* Wr[5];
    u16* Wh[5]; u16* Wlo[5];
};
__global__ void k_packw5(PackArgs pa) {
    int L   = blockIdx.y;
    int idx = blockIdx.x * 256 + threadIdx.x;
    if (idx >= 128 * 256) return;
    int j = idx & 7, l = (idx >> 3) & 63, s = (idx >> 9) & 7, t = idx >> 12;
    int nrow = t * 16 + (l & 15);
    int k    = s * 32 + (l >> 4) * 8 + j;
    float v  = (k < 128) ? pa.Wl[L][nrow * 128 + k] : pa.Wr[L][nrow * 128 + (k - 128)];
    u16 h = f2bf(v);
    pa.Wh[L][idx]  = h;
    pa.Wlo[L][idx] = f2bf(v - bf2f(h));
}

// ---------------- plane-input MFMA SAGE gemm (BM=128, M=32/wave) ----------------
// All A/X fragments preloaded to registers before the K-loop: the per-step
// vmcnt drain at __syncthreads then only covers W staging issued a full MFMA
// phase earlier -> steady-state stall ~0. A-side uses hi-plane weights only
// (A is bf16-rounded anyway; error same order as agg rounding).
template<int HEAD>
__global__ __launch_bounds__(256, 2) void k_gemm_p(
        const u16* __restrict__ Ahi, const u16* __restrict__ Xh, const u16* __restrict__ Xl,
        const u16* __restrict__ Wh, const u16* __restrict__ Wlo,
        const float* __restrict__ bias, u32* __restrict__ outh, u32* __restrict__ outl,
        const float* __restrict__ hw, const float* __restrict__ hb,
        float* __restrict__ hout, int n) {
    __shared__ __align__(16) u16 smw[2][8192];
    int tid  = threadIdx.x;
    int wave = tid >> 6, lane = tid & 63;
    int rit  = lane & 15, kgrp = lane >> 4;
    int m0   = blockIdx.x * 128 + wave * 32;
    int ar0  = m0 + rit;      if (ar0 > n - 1) ar0 = n - 1;
    int ar1  = m0 + 16 + rit; if (ar1 > n - 1) ar1 = n - 1;

    // full-step stage: 16 slices (8 t x hi/lo), wave stages 4
    #define STAGE(s_, b_) do {                                                   \
        _Pragma("unroll")                                                        \
        for (int q = 0; q < 4; ++q) {                                            \
            int kk = wave * 4 + q;                                               \
            int tt = kk >> 1;                                                    \
            const u16* g = ((kk & 1) ? Wlo : Wh)                                 \
                           + (((tt << 3) + (s_)) << 9) + (lane << 3);            \
            gload_lds16(g, &smw[b_][kk << 9]);                                   \
        }                                                                        \
    } while (0)
    // hi-only stage: 8 even slices, wave stages 2 (for A-side steps)
    #define STAGEH(s_, b_) do {                                                  \
        _Pragma("unroll")                                                        \
        for (int q = 0; q < 2; ++q) {                                            \
            int tt = wave * 2 + q;                                               \
            const u16* g = Wh + (((tt << 3) + (s_)) << 9) + (lane << 3);         \
            gload_lds16(g, &smw[b_][(tt << 1) << 9]);                            \
        }                                                                        \
    } while (0)

    // ---- fragment preload (24 x short8 = 96 VGPR) ----
    short8 a0[4], a1[4], xh0[4], xl0[4], xh1[4], xl1[4];
    #pragma unroll
    for (int s = 0; s < 4; ++s) {
        size_t o0 = (size_t)ar0 * C + s * 32 + kgrp * 8;
        size_t o1 = (size_t)ar1 * C + s * 32 + kgrp * 8;
        a0[s]  = *(const short8*)(Ahi + o0);
        a1[s]  = *(const short8*)(Ahi + o1);
        xh0[s] = *(const short8*)(Xh + o0);
        xl0[s] = *(const short8*)(Xl + o0);
        xh1[s] = *(const short8*)(Xh + o1);
        xl1[s] = *(const short8*)(Xl + o1);
    }

    f32x4 acc0[8], acc1[8];
    #pragma unroll
    for (int t = 0; t < 8; ++t) {
        acc0[t] = (f32x4){0.f, 0.f, 0.f, 0.f};
        acc1[t] = (f32x4){0.f, 0.f, 0.f, 0.f};
    }

    STAGEH(0, 0);
    __syncthreads();

    #pragma unroll
    for (int s = 0; s < 8; ++s) {
        if (s < 7) {
            if (s + 1 < 4) STAGEH(s + 1, (s + 1) & 1);
            else           STAGE(s + 1, (s + 1) & 1);
        }
        const u16* base = smw[s & 1];
        if (s < 4) {
            #pragma unroll
            for (int t = 0; t < 8; ++t) {
                short8 wh = *(const short8*)(base + ((t << 1) << 9) + (lane << 3));
                acc0[t] = __builtin_amdgcn_mfma_f32_16x16x32_bf16(a0[s], wh, acc0[t], 0, 0, 0);
                acc1[t] = __builtin_amdgcn_mfma_f32_16x16x32_bf16(a1[s], wh, acc1[t], 0, 0, 0);
            }
        } else {
            int q = s - 4;
            #pragma unroll
            for (int t = 0; t < 8; ++t) {
                short8 wh = *(const short8*)(base + ((t << 1) << 9)         + (lane << 3));
                short8 wl = *(const short8*)(base + ((((t << 1) | 1)) << 9) + (lane << 3));
                acc0[t] = __builtin_amdgcn_mfma_f32_16x16x32_bf16(xh0[q], wh, acc0[t], 0, 0, 0);
                acc0[t] = __builtin_amdgcn_mfma_f32_16x16x32_bf16(xl0[q], wh, acc0[t], 0, 0, 0);
                acc0[t] = __builtin_amdgcn_mfma_f32_16x16x32_bf16(xh0[q], wl, acc0[t], 0, 0, 0);
                acc1[t] = __builtin_amdgcn_mfma_f32_16x16x32_bf16(xh1[q], wh, acc1[t], 0, 0, 0);
                acc1[t] = __builtin_amdgcn_mfma_f32_16x16x32_bf16(xl1[q], wh, acc1[t], 0, 0, 0);
                acc1[t] = __builtin_amdgcn_mfma_f32_16x16x32_bf16(xh1[q], wl, acc1[t], 0, 0, 0);
            }
        }
        if (s < 7) __syncthreads();
    }
    #undef STAGE
    #undef STAGEH

    if (HEAD) {
        float hsA[4] = {0.f, 0.f, 0.f, 0.f}, hsB[4] = {0.f, 0.f, 0.f, 0.f};
        #pragma unroll
        for (int t = 0; t < 8; ++t) {
            int col = t * 16 + rit;
            float b = bias[col], w = hw[col];
            #pragma unroll
            for (int j = 0; j < 4; ++j) {
                hsA[j] += fmaxf(acc0[t][j] + b, 0.f) * w;
                hsB[j] += fmaxf(acc1[t][j] + b, 0.f) * w;
            }
        }
        #pragma unroll
        for (int msk = 1; msk < 16; msk <<= 1) {
            #pragma unroll
            for (int j = 0; j < 4; ++j) {
                hsA[j] += __shfl_xor(hsA[j], msk, 64);
                hsB[j] += __shfl_xor(hsB[j], msk, 64);
            }
        }
        if (rit == 0) {
            float hbv = hb[0];
            #pragma unroll
            for (int j = 0; j < 4; ++j) {
                int rA = m0 + kgrp * 4 + j;
                int rB = rA + 16;
                if (rA < n) hout[rA] = hsA[j] + hbv;
                if (rB < n) hout[rB] = hsB[j] + hbv;
            }
        }
    } else {
        #pragma unroll
        for (int g = 0; g < 2; ++g) {
            int rbase = m0 + g * 16 + kgrp * 4;
            #pragma unroll
            for (int t = 0; t < 8; ++t) {
                int col = t * 16 + rit;
                float b = bias[col];
                #pragma unroll
                for (int j = 0; j < 4; ++j) {
                    int rr = rbase + j;
                    float v = fmaxf((g ? acc1[t][j] : acc0[t][j]) + b, 0.f);
                    float pv = __shfl_xor(v, 1, 64);
                    if (!(rit & 1) && rr < n) {
                        u16 h  = f2bf(v),              ph  = f2bf(pv);
                        u16 lo = f2bf(v - bf2f(h)),    plo = f2bf(pv - bf2f(ph));
                        outh[(size_t)rr * 64 + (col >> 1)] = ((u32)h)  | (((u32)ph)  << 16);
                        outl[(size_t)rr * 64 + (col >> 1)] = ((u32)lo) | (((u32)plo) << 16);
                    }
                }
            }
        }
    }
}

// ---------------- launch ----------------

extern "C" void kernel_launch(void* const* d_in, const int* in_sizes, int n_in,
                              void* d_out, int out_size, void* d_ws, size_t ws_size,
                              hipStream_t stream) {
    const float* x     = (const float*)d_in[0];
    const int*   ei    = (const int*)d_in[1];
    const int*   src   = ei;
    const int*   dstp  = ei + NE;
    const float* sWl   = (const float*)d_in[2];
    const float* sB    = (const float*)d_in[3];
    const float* sWr   = (const float*)d_in[4];
    const float* rt1Wl = (const float*)d_in[5];
    const float* rt1B  = (const float*)d_in[6];
    const float* rt1Wr = (const float*)d_in[7];
    const float* rt2Wl = (const float*)d_in[8];
    const float* rt2B  = (const float*)d_in[9];
    const float* rt2Wr = (const float*)d_in[10];
    const float* rt3W  = (const float*)d_in[11];
    const float* rt3B  = (const float*)d_in[12];
    const float* mv1Wl = (const float*)d_in[13];
    const float* mv1B  = (const float*)d_in[14];
    const float* mv1Wr = (const float*)d_in[15];
    const float* mv2Wl = (const float*)d_in[16];
    const float* mv2B  = (const float*)d_in[17];
    const float* mv2Wr = (const float*)d_in[18];
    const float* mv3W  = (const float*)d_in[19];
    const float* mv3B  = (const float*)d_in[20];
    float* out = (float*)d_out;

    char* ws = (char*)d_ws;
    int* rowptr  = (int*)ws;                  // NN+1
    int* deg     = rowptr + (NN + 1);         // NN
    int* bsum    = deg + NN;                  // 64
    u16* esrc16  = (u16*)(bsum + 64);         // NE u16
    size_t off   = (((size_t)(NN + 1 + NN + 64) * 4 + (size_t)NE * 2) + 255) & ~(size_t)255;
    // 7 bf16 planes, each NN*64 u32 = 12.8 MB
    u32* P[7];
    for (int i = 0; i < 7; ++i) P[i] = (u32*)(ws + off) + (size_t)i * NN * 64;
    u16* wpack = (u16*)(P[6] + (size_t)NN * 64);
    u16* pk[5][2];
    for (int L = 0; L < 5; ++L) {
        pk[L][0] = wpack + (size_t)L * 65536;
        pk[L][1] = wpack + (size_t)L * 65536 + 32768;
    }

    const int TB = 256;
    const int NB = (NN + 1023) / 1024;
    const int GCH = ((NE + 4095) / 4096) * NR;

    // weight packing (one dispatch) + x plane split
    PackArgs pa;
    pa.Wl[0] = sWl;   pa.Wr[0] = sWr;
    pa.Wl[1] = rt1Wl; pa.Wr[1] = rt1Wr;
    pa.Wl[2] = rt2Wl; pa.Wr[2] = rt2Wr;
    pa.Wl[3] = mv1Wl; pa.Wr[3] = mv1Wr;
    pa.Wl[4] = mv2Wl; pa.Wr[4] = mv2Wr;
    for (int L = 0; L < 5; ++L) { pa.Wh[L] = pk[L][0]; pa.Wlo[L] = pk[L][1]; }
    k_packw5<<<dim3(128, 5), 256, 0, stream>>>(pa);
    k_cvt2<<<(NN * 64 + 255) / 256, 256, 0, stream>>>(x, P[0], P[1], NN * 64);  // xh, xl

    // CSR build (range-partitioned, XCD-affine heuristic)
    k_zero<<<(NN + TB - 1) / TB, TB, 0, stream>>>(deg, NN);
    k_hist_x<<<GCH, 256, 0, stream>>>(dstp, deg, NE);
    k_scan_blk<<<NB, 1024, 0, stream>>>(deg, rowptr, bsum, NN);
    k_scan_sums<<<1, 64, 0, stream>>>(bsum, NB);
    k_scan_add<<<NB, 1024, 0, stream>>>(rowptr, bsum, NN);
    k_fill_x<<<GCH, 256, 0, stream>>>(src, dstp, rowptr, deg, esrc16, NE);

    dim3 gSeg((NN + 3) / 4), bSeg(256);
    dim3 gGem((NN + 127) / 128), bGem(256);

    // shared layer: mv = relu(sage(x));  agg(x)->P2, mv planes -> P3,P4
    k_segmax_bf<<<gSeg, bSeg, 0, stream>>>(P[0], rowptr, esrc16, P[2], NN);
    k_gemm_p<0><<<gGem, bGem, 0, stream>>>((const u16*)P[2], (const u16*)P[0], (const u16*)P[1],
                                           pk[0][0], pk[0][1], sB, P[3], P[4],
                                           nullptr, nullptr, nullptr, NN);
    // agg(mv) -> P5, shared by rt1 and mv1
    k_segmax_bf<<<gSeg, bSeg, 0, stream>>>(P[3], rowptr, esrc16, P[5], NN);
    k_gemm_p<0><<<gGem, bGem, 0, stream>>>((const u16*)P[5], (const u16*)P[3], (const u16*)P[4],
                                           pk[1][0], pk[1][1], rt1B, P[0], P[1],
                                           nullptr, nullptr, nullptr, NN);   // rt -> P0,P1
    k_gemm_p<0><<<gGem, bGem, 0, stream>>>((const u16*)P[5], (const u16*)P[3], (const u16*)P[4],
                                           pk[3][0], pk[3][1], mv1B, P[2], P[6],
                                           nullptr, nullptr, nullptr, NN);   // md -> P2,P6
    // fused dual aggregation: agg(rt) -> P3, agg(md) -> P4
    k_segmax_bf2<<<gSeg, bSeg, 0, stream>>>(P[0], P[2], rowptr, esrc16, P[3], P[4], NN);
    // rt branch layer 2 + fused rt3 head
    k_gemm_p<1><<<gGem, bGem, 0, stream>>>((const u16*)P[3], (const u16*)P[0], (const u16*)P[1],
                                           pk[2][0], pk[2][1], rt2B, nullptr, nullptr,
                                           rt3W, rt3B, out, NN);
    // md branch layer 2 + fused mv3 head
    k_gemm_p<1><<<gGem, bGem, 0, stream>>>((const u16*)P[4], (const u16*)P[2], (const u16*)P[6],
                                           pk[4][0], pk[4][1], mv2B, nullptr, nullptr,
                                           mv3W, mv3B, out + NN, NN);
}

// Round 10
// 273.750 us; speedup vs baseline: 2.6392x; 1.1888x over previous
//
#include <hip/hip_runtime.h>
#include <hip/hip_bf16.h>
#include <math.h>

#define NN 50000
#define NE 800000
#define C  128
#define NR 8            // dst ranges (XCD-affine via blockIdx%8 heuristic)
#define RNG (NN / NR)
typedef unsigned int u32;
typedef unsigned short u16;

using f32x4  = __attribute__((ext_vector_type(4))) float;
using short8 = __attribute__((ext_vector_type(8))) short;

__device__ __forceinline__ u16 f2bf(float f) {
    u32 u = __float_as_uint(f);
    u32 r = u + 0x7FFFu + ((u >> 16) & 1u);
    return (u16)(r >> 16);
}
__device__ __forceinline__ float bf2f(u16 h) {
    return __uint_as_float(((u32)h) << 16);
}

__device__ __forceinline__ void gload_lds16(const u16* g, u16* l) {
    __builtin_amdgcn_global_load_lds(
        (const __attribute__((address_space(1))) u32*)g,
        (__attribute__((address_space(3))) u32*)l,
        16, 0, 0);
}

// ---------------- CSR build ----------------

__global__ void k_zero(int* __restrict__ p, int n) {
    int i = blockIdx.x * blockDim.x + threadIdx.x;
    if (i < n) p[i] = 0;
}

__global__ __launch_bounds__(256) void k_hist_x(const int* __restrict__ dst, int* __restrict__ deg, int nE) {
    int r    = blockIdx.x & (NR - 1);
    int base = (blockIdx.x >> 3) * 4096;
    int lo   = r * RNG, hi = lo + RNG;
    #pragma unroll
    for (int it = 0; it < 16; ++it) {
        int e = base + it * 256 + threadIdx.x;
        if (e < nE) {
            int d = dst[e];
            if (d >= lo && d < hi) atomicAdd(&deg[d], 1);
        }
    }
}

__global__ __launch_bounds__(1024) void k_scan_blk(const int* __restrict__ deg, int* __restrict__ rowptr,
                                                   int* __restrict__ bsum, int n) {
    __shared__ int wsum[16];
    int tid = threadIdx.x, lane = tid & 63, wid = tid >> 6;
    int i = blockIdx.x * 1024 + tid;
    int v = (i < n) ? deg[i] : 0;
    int incl = v;
    #pragma unroll
    for (int d = 1; d < 64; d <<= 1) {
        int t = __shfl_up(incl, d, 64);
        if (lane >= d) incl += t;
    }
    if (lane == 63) wsum[wid] = incl;
    __syncthreads();
    int wo = 0;
    #pragma unroll
    for (int w = 0; w < 16; ++w) wo += (w < wid) ? wsum[w] : 0;
    if (i < n) rowptr[i + 1] = wo + incl;
    if (tid == 1023) bsum[blockIdx.x] = wo + incl;
}

__global__ void k_scan_sums(int* __restrict__ bsum, int nb) {
    int lane = threadIdx.x;
    int v = (lane < nb) ? bsum[lane] : 0;
    int incl = v;
    #pragma unroll
    for (int d = 1; d < 64; d <<= 1) {
        int t = __shfl_up(incl, d, 64);
        if (lane >= d) incl += t;
    }
    if (lane < nb) bsum[lane] = incl - v;  // exclusive
}

__global__ __launch_bounds__(1024) void k_scan_add(int* __restrict__ rowptr, const int* __restrict__ bsum, int n) {
    int i = blockIdx.x * 1024 + threadIdx.x;
    if (i == 0) rowptr[0] = 0;
    if (i < n) rowptr[i + 1] += bsum[blockIdx.x];
}

__global__ __launch_bounds__(256) void k_fill_x(const int* __restrict__ src, const int* __restrict__ dst,
                                                const int* __restrict__ rowptr, int* __restrict__ deg,
                                                u16* __restrict__ esrc, int nE) {
    int r    = blockIdx.x & (NR - 1);
    int base = (blockIdx.x >> 3) * 4096;
    int lo   = r * RNG, hi = lo + RNG;
    #pragma unroll
    for (int it = 0; it < 16; ++it) {
        int e = base + it * 256 + threadIdx.x;
        if (e < nE) {
            int d = dst[e];
            if (d >= lo && d < hi) {
                int old = atomicSub(&deg[d], 1);
                esrc[rowptr[d + 1] - old] = (u16)src[e];
            }
        }
    }
}

// ---------------- fp32 -> packed bf16 (hi plane only) ----------------
__global__ void k_cvt(const float* __restrict__ in, u32* __restrict__ oh, int n64) {
    int i = blockIdx.x * 256 + threadIdx.x;
    if (i < n64) {
        float2 v = *(const float2*)(in + (size_t)i * 2);
        oh[i] = ((u32)f2bf(v.x)) | (((u32)f2bf(v.y)) << 16);
    }
}

// ---------------- segment max over packed bf16 ----------------
#define UPK(w_, lo_, hi_) { lo_ = fmaxf(lo_, __uint_as_float((w_) << 16)); \
                            hi_ = fmaxf(hi_, __uint_as_float((w_) & 0xFFFF0000u)); }

// clamped-slot loop: ceil-to-8, indices clamped to end-1 (max idempotent) -> no scalar tail
__global__ __launch_bounds__(256) void k_segmax_bf(const u32* __restrict__ h2, const int* __restrict__ rowptr,
                                                   const u16* __restrict__ esrc, u32* __restrict__ agg2, int n) {
    int node = blockIdx.x * 4 + (threadIdx.x >> 6);
    int lane = threadIdx.x & 63;
    if (node >= n) return;
    int beg = rowptr[node], end = rowptr[node + 1];
    float mlo = -INFINITY, mhi = -INFINITY;
    int last = end - 1;
    for (int i = beg; i < end; i += 8) {
        int e0 = i,     e1 = i + 1, e2 = i + 2, e3 = i + 3;
        int e4 = i + 4, e5 = i + 5, e6 = i + 6, e7 = i + 7;
        e1 = e1 > last ? last : e1;  e2 = e2 > last ? last : e2;
        e3 = e3 > last ? last : e3;  e4 = e4 > last ? last : e4;
        e5 = e5 > last ? last : e5;  e6 = e6 > last ? last : e6;
        e7 = e7 > last ? last : e7;
        u32 w0 = h2[((size_t)esrc[e0] << 6) + lane];
        u32 w1 = h2[((size_t)esrc[e1] << 6) + lane];
        u32 w2 = h2[((size_t)esrc[e2] << 6) + lane];
        u32 w3 = h2[((size_t)esrc[e3] << 6) + lane];
        u32 w4 = h2[((size_t)esrc[e4] << 6) + lane];
        u32 w5 = h2[((size_t)esrc[e5] << 6) + lane];
        u32 w6 = h2[((size_t)esrc[e6] << 6) + lane];
        u32 w7 = h2[((size_t)esrc[e7] << 6) + lane];
        UPK(w0, mlo, mhi) UPK(w1, mlo, mhi) UPK(w2, mlo, mhi) UPK(w3, mlo, mhi)
        UPK(w4, mlo, mhi) UPK(w5, mlo, mhi) UPK(w6, mlo, mhi) UPK(w7, mlo, mhi)
    }
    u32 r = 0u;
    if (end > beg)
        r = (__float_as_uint(mlo) >> 16) | (__float_as_uint(mhi) & 0xFFFF0000u);
    __builtin_nontemporal_store(r, &agg2[(size_t)node * 64 + lane]);
}

// dual: two feature arrays over the same edges, 16 gathers in flight
__global__ __launch_bounds__(256) void k_segmax_bf2(const u32* __restrict__ hA, const u32* __restrict__ hB,
                                                    const int* __restrict__ rowptr, const u16* __restrict__ esrc,
                                                    u32* __restrict__ aggA, u32* __restrict__ aggB, int n) {
    int node = blockIdx.x * 4 + (threadIdx.x >> 6);
    int lane = threadIdx.x & 63;
    if (node >= n) return;
    int beg = rowptr[node], end = rowptr[node + 1];
    float alo = -INFINITY, ahi = -INFINITY, blo = -INFINITY, bhi = -INFINITY;
    int last = end - 1;
    for (int i = beg; i < end; i += 8) {
        int e0 = i,     e1 = i + 1, e2 = i + 2, e3 = i + 3;
        int e4 = i + 4, e5 = i + 5, e6 = i + 6, e7 = i + 7;
        e1 = e1 > last ? last : e1;  e2 = e2 > last ? last : e2;
        e3 = e3 > last ? last : e3;  e4 = e4 > last ? last : e4;
        e5 = e5 > last ? last : e5;  e6 = e6 > last ? last : e6;
        e7 = e7 > last ? last : e7;
        size_t b0 = ((size_t)esrc[e0] << 6) + lane;
        size_t b1 = ((size_t)esrc[e1] << 6) + lane;
        size_t b2 = ((size_t)esrc[e2] << 6) + lane;
        size_t b3 = ((size_t)esrc[e3] << 6) + lane;
        size_t b4 = ((size_t)esrc[e4] << 6) + lane;
        size_t b5 = ((size_t)esrc[e5] << 6) + lane;
        size_t b6 = ((size_t)esrc[e6] << 6) + lane;
        size_t b7 = ((size_t)esrc[e7] << 6) + lane;
        u32 a0 = hA[b0], a1 = hA[b1], a2 = hA[b2], a3 = hA[b3];
        u32 a4 = hA[b4], a5 = hA[b5], a6 = hA[b6], a7 = hA[b7];
        u32 q0 = hB[b0], q1 = hB[b1], q2 = hB[b2], q3 = hB[b3];
        u32 q4 = hB[b4], q5 = hB[b5], q6 = hB[b6], q7 = hB[b7];
        UPK(a0, alo, ahi) UPK(a1, alo, ahi) UPK(a2, alo, ahi) UPK(a3, alo, ahi)
        UPK(a4, alo, ahi) UPK(a5, alo, ahi) UPK(a6, alo, ahi) UPK(a7, alo, ahi)
        UPK(q0, blo, bhi) UPK(q1, blo, bhi) UPK(q2, blo, bhi) UPK(q3, blo, bhi)
        UPK(q4, blo, bhi) UPK(q5, blo, bhi) UPK(q6, blo, bhi) UPK(q7, blo, bhi)
    }
    u32 ra = 0u, rb = 0u;
    if (end > beg) {
        ra = (__float_as_uint(alo) >> 16) | (__float_as_uint(ahi) & 0xFFFF0000u);
        rb = (__float_as_uint(blo) >> 16) | (__float_as_uint(bhi) & 0xFFFF0000u);
    }
    __builtin_nontemporal_store(ra, &aggA[(size_t)node * 64 + lane]);
    __builtin_nontemporal_store(rb, &aggB[(size_t)node * 64 + lane]);
}

// ---------------- weight pack: all 5 layers in one dispatch ----------------
struct PackArgs {
    const float* Wl[5]; const float* Wr[5];
    u16* Wh[5]; u16* Wlo[5];
};
__global__ void k_packw5(PackArgs pa) {
    int L   = blockIdx.y;
    int idx = blockIdx.x * 256 + threadIdx.x;
    if (idx >= 128 * 256) return;
    int j = idx & 7, l = (idx >> 3) & 63, s = (idx >> 9) & 7, t = idx >> 12;
    int nrow = t * 16 + (l & 15);
    int k    = s * 32 + (l >> 4) * 8 + j;
    float v  = (k < 128) ? pa.Wl[L][nrow * 128 + k] : pa.Wr[L][nrow * 128 + (k - 128)];
    u16 h = f2bf(v);
    pa.Wh[L][idx]  = h;
    pa.Wlo[L][idx] = f2bf(v - bf2f(h));
}

// ---------------- plane-input MFMA SAGE gemm (BM=128, M=32/wave) ----------------
// Single-bf16-plane activations. A-phase (s<4): a·wh. X-phase (s>=4): xh·wh + xh·wl
// (W at split precision, X at bf16). Output: single bf16 plane. HEAD: fused 128->1.
template<int HEAD>
__global__ __launch_bounds__(256, 2) void k_gemm_p(
        const u16* __restrict__ Ahi, const u16* __restrict__ Xh,
        const u16* __restrict__ Wh, const u16* __restrict__ Wlo,
        const float* __restrict__ bias, u32* __restrict__ outh,
        const float* __restrict__ hw, const float* __restrict__ hb,
        float* __restrict__ hout, int n) {
    __shared__ __align__(16) u16 smw[2][8192];
    int tid  = threadIdx.x;
    int wave = tid >> 6, lane = tid & 63;
    int rit  = lane & 15, kgrp = lane >> 4;
    int m0   = blockIdx.x * 128 + wave * 32;
    int ar0  = m0 + rit;      if (ar0 > n - 1) ar0 = n - 1;
    int ar1  = m0 + 16 + rit; if (ar1 > n - 1) ar1 = n - 1;

    #define STAGE(s_, b_) do {                                                   \
        _Pragma("unroll")                                                        \
        for (int q = 0; q < 4; ++q) {                                            \
            int kk = wave * 4 + q;                                               \
            int tt = kk >> 1;                                                    \
            const u16* g = ((kk & 1) ? Wlo : Wh)                                 \
                           + (((tt << 3) + (s_)) << 9) + (lane << 3);            \
            gload_lds16(g, &smw[b_][kk << 9]);                                   \
        }                                                                        \
    } while (0)
    #define STAGEH(s_, b_) do {                                                  \
        _Pragma("unroll")                                                        \
        for (int q = 0; q < 2; ++q) {                                            \
            int tt = wave * 2 + q;                                               \
            const u16* g = Wh + (((tt << 3) + (s_)) << 9) + (lane << 3);         \
            gload_lds16(g, &smw[b_][(tt << 1) << 9]);                            \
        }                                                                        \
    } while (0)

    // fragment preload: 16 x short8 = 64 VGPR
    short8 a0[4], a1[4], xh0[4], xh1[4];
    #pragma unroll
    for (int s = 0; s < 4; ++s) {
        size_t o0 = (size_t)ar0 * C + s * 32 + kgrp * 8;
        size_t o1 = (size_t)ar1 * C + s * 32 + kgrp * 8;
        a0[s]  = *(const short8*)(Ahi + o0);
        a1[s]  = *(const short8*)(Ahi + o1);
        xh0[s] = *(const short8*)(Xh + o0);
        xh1[s] = *(const short8*)(Xh + o1);
    }

    f32x4 acc0[8], acc1[8];
    #pragma unroll
    for (int t = 0; t < 8; ++t) {
        acc0[t] = (f32x4){0.f, 0.f, 0.f, 0.f};
        acc1[t] = (f32x4){0.f, 0.f, 0.f, 0.f};
    }

    STAGEH(0, 0);
    __syncthreads();

    #pragma unroll
    for (int s = 0; s < 8; ++s) {
        if (s < 7) {
            if (s + 1 < 4) STAGEH(s + 1, (s + 1) & 1);
            else           STAGE(s + 1, (s + 1) & 1);
        }
        const u16* base = smw[s & 1];
        if (s < 4) {
            #pragma unroll
            for (int t = 0; t < 8; ++t) {
                short8 wh = *(const short8*)(base + ((t << 1) << 9) + (lane << 3));
                acc0[t] = __builtin_amdgcn_mfma_f32_16x16x32_bf16(a0[s], wh, acc0[t], 0, 0, 0);
                acc1[t] = __builtin_amdgcn_mfma_f32_16x16x32_bf16(a1[s], wh, acc1[t], 0, 0, 0);
            }
        } else {
            int q = s - 4;
            #pragma unroll
            for (int t = 0; t < 8; ++t) {
                short8 wh = *(const short8*)(base + ((t << 1) << 9)         + (lane << 3));
                short8 wl = *(const short8*)(base + ((((t << 1) | 1)) << 9) + (lane << 3));
                acc0[t] = __builtin_amdgcn_mfma_f32_16x16x32_bf16(xh0[q], wh, acc0[t], 0, 0, 0);
                acc0[t] = __builtin_amdgcn_mfma_f32_16x16x32_bf16(xh0[q], wl, acc0[t], 0, 0, 0);
                acc1[t] = __builtin_amdgcn_mfma_f32_16x16x32_bf16(xh1[q], wh, acc1[t], 0, 0, 0);
                acc1[t] = __builtin_amdgcn_mfma_f32_16x16x32_bf16(xh1[q], wl, acc1[t], 0, 0, 0);
            }
        }
        if (s < 7) __syncthreads();
    }
    #undef STAGE
    #undef STAGEH

    if (HEAD) {
        float hsA[4] = {0.f, 0.f, 0.f, 0.f}, hsB[4] = {0.f, 0.f, 0.f, 0.f};
        #pragma unroll
        for (int t = 0; t < 8; ++t) {
            int col = t * 16 + rit;
            float b = bias[col], w = hw[col];
            #pragma unroll
            for (int j = 0; j < 4; ++j) {
                hsA[j] += fmaxf(acc0[t][j] + b, 0.f) * w;
                hsB[j] += fmaxf(acc1[t][j] + b, 0.f) * w;
            }
        }
        #pragma unroll
        for (int msk = 1; msk < 16; msk <<= 1) {
            #pragma unroll
            for (int j = 0; j < 4; ++j) {
                hsA[j] += __shfl_xor(hsA[j], msk, 64);
                hsB[j] += __shfl_xor(hsB[j], msk, 64);
            }
        }
        if (rit == 0) {
            float hbv = hb[0];
            #pragma unroll
            for (int j = 0; j < 4; ++j) {
                int rA = m0 + kgrp * 4 + j;
                int rB = rA + 16;
                if (rA < n) hout[rA] = hsA[j] + hbv;
                if (rB < n) hout[rB] = hsB[j] + hbv;
            }
        }
    } else {
        #pragma unroll
        for (int g = 0; g < 2; ++g) {
            int rbase = m0 + g * 16 + kgrp * 4;
            #pragma unroll
            for (int t = 0; t < 8; ++t) {
                int col = t * 16 + rit;
                float b = bias[col];
                #pragma unroll
                for (int j = 0; j < 4; ++j) {
                    int rr = rbase + j;
                    float v = fmaxf((g ? acc1[t][j] : acc0[t][j]) + b, 0.f);
                    float pv = __shfl_xor(v, 1, 64);
                    if (!(rit & 1) && rr < n)
                        outh[(size_t)rr * 64 + (col >> 1)] = ((u32)f2bf(v)) | (((u32)f2bf(pv)) << 16);
                }
            }
        }
    }
}

// dual-output: two weight sets against the same (A, X); one read of A/X planes.
__global__ __launch_bounds__(256, 2) void k_gemm_p2(
        const u16* __restrict__ Ahi, const u16* __restrict__ Xh,
        const u16* __restrict__ Wh1, const u16* __restrict__ Wlo1,
        const float* __restrict__ b1, u32* __restrict__ out1,
        const u16* __restrict__ Wh2, const u16* __restrict__ Wlo2,
        const float* __restrict__ b2, u32* __restrict__ out2, int n) {
    __shared__ __align__(16) u16 smw[2][16384];  // 2 sets x 16 slices x 512
    int tid  = threadIdx.x;
    int wave = tid >> 6, lane = tid & 63;
    int rit  = lane & 15, kgrp = lane >> 4;
    int m0   = blockIdx.x * 128 + wave * 32;
    int ar0  = m0 + rit;      if (ar0 > n - 1) ar0 = n - 1;
    int ar1  = m0 + 16 + rit; if (ar1 > n - 1) ar1 = n - 1;

    #define STAGE2(s_, b_) do {                                                  \
        _Pragma("unroll")                                                        \
        for (int q = 0; q < 8; ++q) {                                            \
            int kk = wave * 8 + q;                                               \
            int set = kk >> 4, sl = kk & 15;                                     \
            int tt = sl >> 1;                                                    \
            const u16* g = ((sl & 1) ? (set ? Wlo2 : Wlo1) : (set ? Wh2 : Wh1))  \
                           + (((tt << 3) + (s_)) << 9) + (lane << 3);            \
            gload_lds16(g, &smw[b_][set * 8192 + (sl << 9)]);                    \
        }                                                                        \
    } while (0)
    #define STAGE2H(s_, b_) do {                                                 \
        _Pragma("unroll")                                                        \
        for (int q = 0; q < 4; ++q) {                                            \
            int kk = wave * 4 + q;                                               \
            int set = kk >> 3, tt = kk & 7;                                      \
            const u16* g = (set ? Wh2 : Wh1)                                     \
                           + (((tt << 3) + (s_)) << 9) + (lane << 3);            \
            gload_lds16(g, &smw[b_][set * 8192 + ((tt << 1) << 9)]);             \
        }                                                                        \
    } while (0)

    short8 a0[4], a1[4], xh0[4], xh1[4];
    #pragma unroll
    for (int s = 0; s < 4; ++s) {
        size_t o0 = (size_t)ar0 * C + s * 32 + kgrp * 8;
        size_t o1 = (size_t)ar1 * C + s * 32 + kgrp * 8;
        a0[s]  = *(const short8*)(Ahi + o0);
        a1[s]  = *(const short8*)(Ahi + o1);
        xh0[s] = *(const short8*)(Xh + o0);
        xh1[s] = *(const short8*)(Xh + o1);
    }

    f32x4 acc[2][2][8];
    #pragma unroll
    for (int e = 0; e < 2; ++e)
        #pragma unroll
        for (int g = 0; g < 2; ++g)
            #pragma unroll
            for (int t = 0; t < 8; ++t) acc[e][g][t] = (f32x4){0.f, 0.f, 0.f, 0.f};

    STAGE2H(0, 0);
    __syncthreads();

    #pragma unroll
    for (int s = 0; s < 8; ++s) {
        if (s < 7) {
            if (s + 1 < 4) STAGE2H(s + 1, (s + 1) & 1);
            else           STAGE2(s + 1, (s + 1) & 1);
        }
        const u16* base = smw[s & 1];
        if (s < 4) {
            #pragma unroll
            for (int e = 0; e < 2; ++e) {
                const u16* sb = base + e * 8192;
                #pragma unroll
                for (int t = 0; t < 8; ++t) {
                    short8 wh = *(const short8*)(sb + ((t << 1) << 9) + (lane << 3));
                    acc[e][0][t] = __builtin_amdgcn_mfma_f32_16x16x32_bf16(a0[s], wh, acc[e][0][t], 0, 0, 0);
                    acc[e][1][t] = __builtin_amdgcn_mfma_f32_16x16x32_bf16(a1[s], wh, acc[e][1][t], 0, 0, 0);
                }
            }
        } else {
            int q = s - 4;
            #pragma unroll
            for (int e = 0; e < 2; ++e) {
                const u16* sb = base + e * 8192;
                #pragma unroll
                for (int t = 0; t < 8; ++t) {
                    short8 wh = *(const short8*)(sb + ((t << 1) << 9)         + (lane << 3));
                    short8 wl = *(const short8*)(sb + ((((t << 1) | 1)) << 9) + (lane << 3));
                    acc[e][0][t] = __builtin_amdgcn_mfma_f32_16x16x32_bf16(xh0[q], wh, acc[e][0][t], 0, 0, 0);
                    acc[e][0][t] = __builtin_amdgcn_mfma_f32_16x16x32_bf16(xh0[q], wl, acc[e][0][t], 0, 0, 0);
                    acc[e][1][t] = __builtin_amdgcn_mfma_f32_16x16x32_bf16(xh1[q], wh, acc[e][1][t], 0, 0, 0);
                    acc[e][1][t] = __builtin_amdgcn_mfma_f32_16x16x32_bf16(xh1[q], wl, acc[e][1][t], 0, 0, 0);
                }
            }
        }
        if (s < 7) __syncthreads();
    }
    #undef STAGE2
    #undef STAGE2H

    #pragma unroll
    for (int e = 0; e < 2; ++e) {
        const float* bb = e ? b2 : b1;
        u32* oo = e ? out2 : out1;
        #pragma unroll
        for (int g = 0; g < 2; ++g) {
            int rbase = m0 + g * 16 + kgrp * 4;
            #pragma unroll
            for (int t = 0; t < 8; ++t) {
                int col = t * 16 + rit;
                float b = bb[col];
                #pragma unroll
                for (int j = 0; j < 4; ++j) {
                    int rr = rbase + j;
                    float v = fmaxf(acc[e][g][t][j] + b, 0.f);
                    float pv = __shfl_xor(v, 1, 64);
                    if (!(rit & 1) && rr < n)
                        oo[(size_t)rr * 64 + (col >> 1)] = ((u32)f2bf(v)) | (((u32)f2bf(pv)) << 16);
                }
            }
        }
    }
}

// ---------------- launch ----------------

extern "C" void kernel_launch(void* const* d_in, const int* in_sizes, int n_in,
                              void* d_out, int out_size, void* d_ws, size_t ws_size,
                              hipStream_t stream) {
    const float* x     = (const float*)d_in[0];
    const int*   ei    = (const int*)d_in[1];
    const int*   src   = ei;
    const int*   dstp  = ei + NE;
    const float* sWl   = (const float*)d_in[2];
    const float* sB    = (const float*)d_in[3];
    const float* sWr   = (const float*)d_in[4];
    const float* rt1Wl = (const float*)d_in[5];
    const float* rt1B  = (const float*)d_in[6];
    const float* rt1Wr = (const float*)d_in[7];
    const float* rt2Wl = (const float*)d_in[8];
    const float* rt2B  = (const float*)d_in[9];
    const float* rt2Wr = (const float*)d_in[10];
    const float* rt3W  = (const float*)d_in[11];
    const float* rt3B  = (const float*)d_in[12];
    const float* mv1Wl = (const float*)d_in[13];
    const float* mv1B  = (const float*)d_in[14];
    const float* mv1Wr = (const float*)d_in[15];
    const float* mv2Wl = (const float*)d_in[16];
    const float* mv2B  = (const float*)d_in[17];
    const float* mv2Wr = (const float*)d_in[18];
    const float* mv3W  = (const float*)d_in[19];
    const float* mv3B  = (const float*)d_in[20];
    float* out = (float*)d_out;

    char* ws = (char*)d_ws;
    int* rowptr  = (int*)ws;                  // NN+1
    int* deg     = rowptr + (NN + 1);         // NN
    int* bsum    = deg + NN;                  // 64
    u16* esrc16  = (u16*)(bsum + 64);         // NE u16
    size_t off   = (((size_t)(NN + 1 + NN + 64) * 4 + (size_t)NE * 2) + 255) & ~(size_t)255;
    // 5 bf16 planes, each NN*64 u32 = 12.8 MB
    u32* P[5];
    for (int i = 0; i < 5; ++i) P[i] = (u32*)(ws + off) + (size_t)i * NN * 64;
    u16* wpack = (u16*)(P[4] + (size_t)NN * 64);
    u16* pk[5][2];
    for (int L = 0; L < 5; ++L) {
        pk[L][0] = wpack + (size_t)L * 65536;
        pk[L][1] = wpack + (size_t)L * 65536 + 32768;
    }

    const int TB = 256;
    const int NB = (NN + 1023) / 1024;
    const int GCH = ((NE + 4095) / 4096) * NR;

    // weight packing (one dispatch) + x hi-plane conversion
    PackArgs pa;
    pa.Wl[0] = sWl;   pa.Wr[0] = sWr;
    pa.Wl[1] = rt1Wl; pa.Wr[1] = rt1Wr;
    pa.Wl[2] = rt2Wl; pa.Wr[2] = rt2Wr;
    pa.Wl[3] = mv1Wl; pa.Wr[3] = mv1Wr;
    pa.Wl[4] = mv2Wl; pa.Wr[4] = mv2Wr;
    for (int L = 0; L < 5; ++L) { pa.Wh[L] = pk[L][0]; pa.Wlo[L] = pk[L][1]; }
    k_packw5<<<dim3(128, 5), 256, 0, stream>>>(pa);
    k_cvt<<<(NN * 64 + 255) / 256, 256, 0, stream>>>(x, P[0], NN * 64);  // xh -> P0

    // CSR build (range-partitioned, XCD-affine heuristic)
    k_zero<<<(NN + TB - 1) / TB, TB, 0, stream>>>(deg, NN);
    k_hist_x<<<GCH, 256, 0, stream>>>(dstp, deg, NE);
    k_scan_blk<<<NB, 1024, 0, stream>>>(deg, rowptr, bsum, NN);
    k_scan_sums<<<1, 64, 0, stream>>>(bsum, NB);
    k_scan_add<<<NB, 1024, 0, stream>>>(rowptr, bsum, NN);
    k_fill_x<<<GCH, 256, 0, stream>>>(src, dstp, rowptr, deg, esrc16, NE);

    dim3 gSeg((NN + 3) / 4), bSeg(256);
    dim3 gGem((NN + 127) / 128), bGem(256);

    // shared layer: agg(x)->P1; mv = relu(sage(x)) -> P2
    k_segmax_bf<<<gSeg, bSeg, 0, stream>>>(P[0], rowptr, esrc16, P[1], NN);
    k_gemm_p<0><<<gGem, bGem, 0, stream>>>((const u16*)P[1], (const u16*)P[0],
                                           pk[0][0], pk[0][1], sB, P[2],
                                           nullptr, nullptr, nullptr, NN);
    // agg(mv) -> P3; dual GEMM: rt -> P1, md -> P4
    k_segmax_bf<<<gSeg, bSeg, 0, stream>>>(P[2], rowptr, esrc16, P[3], NN);
    k_gemm_p2<<<gGem, bGem, 0, stream>>>((const u16*)P[3], (const u16*)P[2],
                                         pk[1][0], pk[1][1], rt1B, P[1],
                                         pk[3][0], pk[3][1], mv1B, P[4], NN);
    // fused dual aggregation: agg(rt) -> P0, agg(md) -> P3
    k_segmax_bf2<<<gSeg, bSeg, 0, stream>>>(P[1], P[4], rowptr, esrc16, P[0], P[3], NN);
    // rt branch layer 2 + fused rt3 head
    k_gemm_p<1><<<gGem, bGem, 0, stream>>>((const u16*)P[0], (const u16*)P[1],
                                           pk[2][0], pk[2][1], rt2B, nullptr,
                                           rt3W, rt3B, out, NN);
    // md branch layer 2 + fused mv3 head
    k_gemm_p<1><<<gGem, bGem, 0, stream>>>((const u16*)P[3], (const u16*)P[4],
                                           pk[4][0], pk[4][1], mv2B, nullptr,
                                           mv3W, mv3B, out + NN, NN);
}